// Round 2
// baseline (529.375 us; speedup 1.0000x reference)
//
#include <hip/hip_runtime.h>

typedef float  f32x4  __attribute__((ext_vector_type(4)));
typedef __bf16 bf16x8 __attribute__((ext_vector_type(8)));
typedef __bf16 bf16x4 __attribute__((ext_vector_type(4)));
typedef unsigned short u16x8 __attribute__((ext_vector_type(8)));

__device__ __forceinline__ unsigned short f2bf(float f) {
    unsigned u = __builtin_bit_cast(unsigned, f);
    unsigned r = u + 0x7FFFu + ((u >> 16) & 1u);   // round-to-nearest-even
    return (unsigned short)(r >> 16);
}

__device__ __forceinline__ f32x4 mfma16(bf16x8 a, bf16x8 b, f32x4 c) {
    return __builtin_amdgcn_mfma_f32_16x16x32_bf16(a, b, c, 0, 0, 0);
}
__device__ __forceinline__ f32x4 mfma16u(u16x8 a, u16x8 b, f32x4 c) {
    return __builtin_amdgcn_mfma_f32_16x16x32_bf16(
        __builtin_bit_cast(bf16x8, a), __builtin_bit_cast(bf16x8, b), c, 0, 0, 0);
}

// ---------------- cast fp32 -> bf16 (8 elems / thread) ----------------
__global__ __launch_bounds__(256) void cast_bf16(const float* __restrict__ in,
                                                 unsigned short* __restrict__ out) {
    int t = blockIdx.x * 256 + threadIdx.x;
    const float* p = in + (size_t)t * 8;
    f32x4 a = *(const f32x4*)p;
    f32x4 b = *(const f32x4*)(p + 4);
    u16x8 o;
    o[0] = f2bf(a[0]); o[1] = f2bf(a[1]); o[2] = f2bf(a[2]); o[3] = f2bf(a[3]);
    o[4] = f2bf(b[0]); o[5] = f2bf(b[1]); o[6] = f2bf(b[2]); o[7] = f2bf(b[3]);
    *(u16x8*)(out + (size_t)t * 8) = o;
}

// ---- cast + transpose 1024x1024 fp32 W[k][n] -> bf16 Wt[n][k], LDS tiled ----
__global__ __launch_bounds__(256) void cast_transpose2(const float* __restrict__ W,
                                                       __bf16* __restrict__ Wt) {
    __shared__ __bf16 T[64][64];     // XOR-granule swizzled
    const int tid = threadIdx.x;
    const int k0 = blockIdx.y * 64, n0 = blockIdx.x * 64;
#pragma unroll
    for (int c = 0; c < 4; ++c) {
        int idx = c * 256 + tid;                 // 0..1023
        int kr = idx >> 4, nc = (idx & 15) * 4;
        f32x4 w = *(const f32x4*)&W[(size_t)(k0 + kr) * 1024 + n0 + nc];
        int g = ((nc >> 3) ^ (kr >> 3)) * 8 + (nc & 7);
        bf16x4 pk;
        pk[0] = (__bf16)w[0]; pk[1] = (__bf16)w[1];
        pk[2] = (__bf16)w[2]; pk[3] = (__bf16)w[3];
        *(bf16x4*)&T[kr][g] = pk;
    }
    __syncthreads();
#pragma unroll
    for (int c = 0; c < 2; ++c) {
        int idx = c * 256 + tid;                 // 0..511
        int n = idx >> 3, k8 = (idx & 7) * 8;
        bf16x8 o;
#pragma unroll
        for (int e = 0; e < 8; ++e) {
            int k = k8 + e;
            o[e] = T[k][((n >> 3) ^ (k >> 3)) * 8 + (n & 7)];
        }
        *(bf16x8*)&Wt[(size_t)(n0 + n) * 1024 + k0 + k8] = o;
    }
}

// ---- per-head transpose: qkv[b][n][h*64+d] -> vT[(b*16+h)][d][n] ----
__global__ __launch_bounds__(256) void transpose_v(const __bf16* __restrict__ qkv,
                                                   __bf16* __restrict__ vT) {
    __shared__ __bf16 T[64][64];     // XOR-granule swizzled
    const int tid = threadIdx.x;
    const int b = blockIdx.z, h = blockIdx.y, n0 = blockIdx.x * 64;
#pragma unroll
    for (int c = 0; c < 2; ++c) {
        int idx = c * 256 + tid;                 // 0..511
        int nr = idx >> 3, d8 = (idx & 7) * 8;
        bf16x8 v = *(const bf16x8*)&qkv[((size_t)b * 2048 + n0 + nr) * 1024 + h * 64 + d8];
        int g = ((d8 >> 3) ^ (nr >> 3)) * 8;
        *(bf16x8*)&T[nr][g] = v;
    }
    __syncthreads();
    const size_t ob = (size_t)(b * 16 + h) * 64 * 2048;
#pragma unroll
    for (int c = 0; c < 2; ++c) {
        int idx = c * 256 + tid;
        int d = idx >> 3, n8 = (idx & 7) * 8;
        bf16x8 o;
#pragma unroll
        for (int e = 0; e < 8; ++e) {
            int row = n8 + e;
            o[e] = T[row][((d >> 3) ^ (row >> 3)) * 8 + (d & 7)];
        }
        *(bf16x8*)&vT[ob + (size_t)d * 2048 + n0 + n8] = o;
    }
}

// ---------------- GEMM (unchanged from round 1, passing) ----------------
template <bool OUT_BF16>
__global__ __launch_bounds__(256) void gemm_bt(const unsigned short* __restrict__ A,
                                               const unsigned short* __restrict__ Bt,
                                               void* __restrict__ Cout,
                                               const float* __restrict__ bias) {
    constexpr int K = 1024, NN = 1024;
    __shared__ unsigned short As[128][72];
    __shared__ unsigned short Bs[128][72];
    const int tid  = threadIdx.x;
    const int lane = tid & 63, wid = tid >> 6;
    const int wm = wid >> 1, wn = wid & 1;
    const int i = lane & 15, q8 = (lane >> 4) * 8;
    const int tm = blockIdx.y * 128, tn = blockIdx.x * 128;
    const int srow = tid >> 3, scol = (tid & 7) * 8;

    f32x4 acc[4][4] = {};

    for (int k0 = 0; k0 < K; k0 += 64) {
#pragma unroll
        for (int c = 0; c < 4; ++c) {
            int row = c * 32 + srow;
            u16x8 av = *(const u16x8*)&A [(size_t)(tm + row) * K + k0 + scol];
            u16x8 bv = *(const u16x8*)&Bt[(size_t)(tn + row) * K + k0 + scol];
            *(u16x8*)&As[row][scol] = av;
            *(u16x8*)&Bs[row][scol] = bv;
        }
        __syncthreads();
#pragma unroll
        for (int ks = 0; ks < 2; ++ks) {
            u16x8 af[4], bfr[4];
#pragma unroll
            for (int m = 0; m < 4; ++m) af[m]  = *(const u16x8*)&As[wm * 64 + m * 16 + i][ks * 32 + q8];
#pragma unroll
            for (int n = 0; n < 4; ++n) bfr[n] = *(const u16x8*)&Bs[wn * 64 + n * 16 + i][ks * 32 + q8];
#pragma unroll
            for (int m = 0; m < 4; ++m)
#pragma unroll
                for (int n = 0; n < 4; ++n)
                    acc[m][n] = mfma16u(af[m], bfr[n], acc[m][n]);
        }
        __syncthreads();
    }

    const int r0 = (lane >> 4) * 4;
#pragma unroll
    for (int n = 0; n < 4; ++n) {
        int col = tn + wn * 64 + n * 16 + i;
        float bv = 0.f;
        if constexpr (!OUT_BF16) bv = bias[col];
#pragma unroll
        for (int m = 0; m < 4; ++m) {
            int rowb = tm + wm * 64 + m * 16 + r0;
#pragma unroll
            for (int r = 0; r < 4; ++r) {
                if constexpr (OUT_BF16)
                    ((unsigned short*)Cout)[(size_t)(rowb + r) * NN + col] = f2bf(acc[m][n][r]);
                else
                    ((float*)Cout)[(size_t)(rowb + r) * NN + col] = acc[m][n][r] + bv;
            }
        }
    }
}

// ---------------- Flash attention v2: no K/V staging, swapped QK^T ----------------
// grid (32 q-tiles, 16 heads, 4 batch), 256 threads = 4 independent waves x 16 q-rows.
__global__ __launch_bounds__(256) void flash_attn2(const __bf16* __restrict__ qkv,
                                                   const __bf16* __restrict__ vT,
                                                   __bf16* __restrict__ attnout) {
    __shared__ __bf16 Pl[4][16][88];   // per-wave P tile [q][k], stride 88 (16B-aligned, ~2-way)
    const int tid = threadIdx.x, lane = tid & 63, wid = tid >> 6;
    const int i = lane & 15, qg = lane >> 4;
    const int b = blockIdx.z, h = blockIdx.y, q0 = blockIdx.x * 64;
    const size_t base  = (size_t)b * 2048 * 1024 + (size_t)h * 64;   // qkv[b][n][h*64+d]
    const size_t vbase = (size_t)(b * 16 + h) * 64 * 2048;           // vT[bh][d][n]

    // Q fragments (B-operand): row q = q0 + wid*16 + i, d-slice s*32 + qg*8
    bf16x8 qf[2];
    const int qrow = q0 + wid * 16 + i;
#pragma unroll
    for (int s = 0; s < 2; ++s)
        qf[s] = *(const bf16x8*)&qkv[base + (size_t)qrow * 1024 + s * 32 + qg * 8];

    float m_run = -1e30f, l_run = 0.f;   // state for q-column i (replicated over qg)
    f32x4 po[4] = {};                    // O rows qg*4+r, cols d = nf*16 + i

    for (int kt = 0; kt < 32; ++kt) {
        const int kv0 = kt * 64;
        // S^T = K Q^T : rows k (m*16 + qg*4 + r), cols q (= i)
        f32x4 st[4];
#pragma unroll
        for (int m = 0; m < 4; ++m) {
            f32x4 a = {};
#pragma unroll
            for (int s = 0; s < 2; ++s) {
                bf16x8 kf = *(const bf16x8*)&qkv[base + (size_t)(kv0 + m * 16 + i) * 1024 + s * 32 + qg * 8];
                a = mfma16(kf, qf[s], a);
            }
            st[m] = a;
        }

        // online softmax over the 64 k-rows of this tile (16 in-lane + 2 shfl)
        float rm = fmaxf(fmaxf(st[0][0], st[0][1]), fmaxf(st[0][2], st[0][3]));
#pragma unroll
        for (int m = 1; m < 4; ++m) {
            float t = fmaxf(fmaxf(st[m][0], st[m][1]), fmaxf(st[m][2], st[m][3]));
            rm = fmaxf(rm, t);
        }
        rm = fmaxf(rm, __shfl_xor(rm, 16));
        rm = fmaxf(rm, __shfl_xor(rm, 32));
        float mnew  = fmaxf(m_run, rm);
        float msc   = mnew * 0.125f;
        float alpha = __expf(fmaf(m_run, 0.125f, -msc));
        m_run = mnew;

        f32x4 psum4 = {};
#pragma unroll
        for (int m = 0; m < 4; ++m) {
            f32x4 p;
#pragma unroll
            for (int r = 0; r < 4; ++r) {
                p[r] = __expf(fmaf(st[m][r], 0.125f, -msc));
            }
            psum4 += p;
            bf16x4 pk;
            pk[0] = (__bf16)p[0]; pk[1] = (__bf16)p[1];
            pk[2] = (__bf16)p[2]; pk[3] = (__bf16)p[3];
            *(bf16x4*)&Pl[wid][i][m * 16 + qg * 4] = pk;   // P[q=i][k]
        }
        float psum = (psum4[0] + psum4[1]) + (psum4[2] + psum4[3]);
        psum += __shfl_xor(psum, 16);
        psum += __shfl_xor(psum, 32);
        l_run = l_run * alpha + psum;

        // redistribute alpha to PV row domain (rows qg*4+r) and rescale O
        float ar[4];
#pragma unroll
        for (int r = 0; r < 4; ++r) ar[r] = __shfl(alpha, qg * 4 + r);
#pragma unroll
        for (int nf = 0; nf < 4; ++nf) {
            po[nf][0] *= ar[0]; po[nf][1] *= ar[1];
            po[nf][2] *= ar[2]; po[nf][3] *= ar[3];
        }

        // cross-lane P visibility (same wave, DS ops in-order; compiler can't see dep)
        asm volatile("s_waitcnt lgkmcnt(0)" ::: "memory");
        __builtin_amdgcn_sched_barrier(0);

        // O += P V  (A = P rows q over k, B = vT rows d over k)
#pragma unroll
        for (int s = 0; s < 2; ++s) {
            bf16x8 pa = *(const bf16x8*)&Pl[wid][i][s * 32 + qg * 8];
#pragma unroll
            for (int nf = 0; nf < 4; ++nf) {
                bf16x8 vf = *(const bf16x8*)&vT[vbase + (size_t)(nf * 16 + i) * 2048 + kv0 + s * 32 + qg * 8];
                po[nf] = mfma16(pa, vf, po[nf]);
            }
        }
        asm volatile("" ::: "memory");   // keep LDS ops from crossing iterations
    }

    // epilogue: normalize rows (l for row q = qg*4+r) and store bf16
    float linv[4];
#pragma unroll
    for (int r = 0; r < 4; ++r) linv[r] = __builtin_amdgcn_rcpf(__shfl(l_run, qg * 4 + r));
#pragma unroll
    for (int nf = 0; nf < 4; ++nf) {
#pragma unroll
        for (int r = 0; r < 4; ++r) {
            int row = q0 + wid * 16 + qg * 4 + r;
            attnout[base + (size_t)row * 1024 + nf * 16 + i] = (__bf16)(po[nf][r] * linv[r]);
        }
    }
}

extern "C" void kernel_launch(void* const* d_in, const int* in_sizes, int n_in,
                              void* d_out, int out_size, void* d_ws, size_t ws_size,
                              hipStream_t stream) {
    const float* x    = (const float*)d_in[0];
    const float* Wqkv = (const float*)d_in[1];
    const float* Wout = (const float*)d_in[2];
    const float* bout = (const float*)d_in[3];
    float* out = (float*)d_out;

    char* ws = (char*)d_ws;
    // [0,16M) xb (x bf16) -> reused as vT after gemm1
    // [16,32M) qkvb ; [32,48M) attn-out ; [48,50M) wqt ; [50,52M) wot
    unsigned short* xb   = (unsigned short*)(ws);
    unsigned short* qkvb = (unsigned short*)(ws + (16u << 20));
    unsigned short* aout = (unsigned short*)(ws + (32u << 20));
    __bf16*         wqt  = (__bf16*)(ws + (48u << 20));
    __bf16*         wot  = (__bf16*)(ws + (50u << 20));
    __bf16*         vTp  = (__bf16*)(ws);            // overlays xb (xb dead after gemm1)

    cast_bf16<<<4096, 256, 0, stream>>>(x, xb);
    cast_transpose2<<<dim3(16, 16), 256, 0, stream>>>(Wqkv, wqt);
    cast_transpose2<<<dim3(16, 16), 256, 0, stream>>>(Wout, wot);

    // qkv = x @ W_qkv   (bf16 out)
    gemm_bt<true><<<dim3(8, 64), 256, 0, stream>>>(xb, (const unsigned short*)wqt, qkvb, nullptr);

    // per-head V^T
    transpose_v<<<dim3(32, 16, 4), 256, 0, stream>>>((const __bf16*)qkvb, vTp);

    // attention
    flash_attn2<<<dim3(32, 16, 4), 256, 0, stream>>>((const __bf16*)qkvb, vTp, (__bf16*)aout);

    // out = attn @ W_out + b   (fp32 out)
    gemm_bt<false><<<dim3(8, 64), 256, 0, stream>>>(aout, (const unsigned short*)wot, out, bout);
}

// Round 3
// 189.051 us; speedup vs baseline: 2.8002x; 2.8002x over previous
//
#include <hip/hip_runtime.h>

typedef float  f32x4  __attribute__((ext_vector_type(4)));
typedef __bf16 bf16x8 __attribute__((ext_vector_type(8)));
typedef __bf16 bf16x4 __attribute__((ext_vector_type(4)));
typedef unsigned short u16x8 __attribute__((ext_vector_type(8)));

__device__ __forceinline__ unsigned short f2bf(float f) {
    unsigned u = __builtin_bit_cast(unsigned, f);
    unsigned r = u + 0x7FFFu + ((u >> 16) & 1u);   // round-to-nearest-even
    return (unsigned short)(r >> 16);
}

__device__ __forceinline__ f32x4 mfma16(bf16x8 a, bf16x8 b, f32x4 c) {
    return __builtin_amdgcn_mfma_f32_16x16x32_bf16(a, b, c, 0, 0, 0);
}
__device__ __forceinline__ f32x4 mfma16u(u16x8 a, u16x8 b, f32x4 c) {
    return __builtin_amdgcn_mfma_f32_16x16x32_bf16(
        __builtin_bit_cast(bf16x8, a), __builtin_bit_cast(bf16x8, b), c, 0, 0, 0);
}

// async global->LDS, 16B per lane, dest = wave-uniform base + lane*16
__device__ __forceinline__ void gload16(const void* g, void* l) {
    __builtin_amdgcn_global_load_lds((const __attribute__((address_space(1))) void*)g,
                                     (__attribute__((address_space(3))) void*)l,
                                     16, 0, 0);
}

// ---------------- cast fp32 -> bf16 (8 elems / thread) ----------------
__global__ __launch_bounds__(256) void cast_bf16(const float* __restrict__ in,
                                                 unsigned short* __restrict__ out) {
    int t = blockIdx.x * 256 + threadIdx.x;
    const float* p = in + (size_t)t * 8;
    f32x4 a = *(const f32x4*)p;
    f32x4 b = *(const f32x4*)(p + 4);
    u16x8 o;
    o[0] = f2bf(a[0]); o[1] = f2bf(a[1]); o[2] = f2bf(a[2]); o[3] = f2bf(a[3]);
    o[4] = f2bf(b[0]); o[5] = f2bf(b[1]); o[6] = f2bf(b[2]); o[7] = f2bf(b[3]);
    *(u16x8*)(out + (size_t)t * 8) = o;
}

// ---- cast + transpose 1024x1024 fp32 W[k][n] -> bf16 Wt[n][k], LDS tiled ----
__global__ __launch_bounds__(256) void cast_transpose2(const float* __restrict__ W,
                                                       __bf16* __restrict__ Wt) {
    __shared__ __bf16 T[64][64];
    const int tid = threadIdx.x;
    const int k0 = blockIdx.y * 64, n0 = blockIdx.x * 64;
#pragma unroll
    for (int c = 0; c < 4; ++c) {
        int idx = c * 256 + tid;
        int kr = idx >> 4, nc = (idx & 15) * 4;
        f32x4 w = *(const f32x4*)&W[(size_t)(k0 + kr) * 1024 + n0 + nc];
        int g = ((nc >> 3) ^ (kr >> 3)) * 8 + (nc & 7);
        bf16x4 pk;
        pk[0] = (__bf16)w[0]; pk[1] = (__bf16)w[1];
        pk[2] = (__bf16)w[2]; pk[3] = (__bf16)w[3];
        *(bf16x4*)&T[kr][g] = pk;
    }
    __syncthreads();
#pragma unroll
    for (int c = 0; c < 2; ++c) {
        int idx = c * 256 + tid;
        int n = idx >> 3, k8 = (idx & 7) * 8;
        bf16x8 o;
#pragma unroll
        for (int e = 0; e < 8; ++e) {
            int k = k8 + e;
            o[e] = T[k][((n >> 3) ^ (k >> 3)) * 8 + (n & 7)];
        }
        *(bf16x8*)&Wt[(size_t)(n0 + n) * 1024 + k0 + k8] = o;
    }
}

// ---- per-head transpose: qkv[b][n][h*64+d] -> vT[(b*16+h)][d][n] ----
__global__ __launch_bounds__(256) void transpose_v(const __bf16* __restrict__ qkv,
                                                   __bf16* __restrict__ vT) {
    __shared__ __bf16 T[64][64];
    const int tid = threadIdx.x;
    const int b = blockIdx.z, h = blockIdx.y, n0 = blockIdx.x * 64;
#pragma unroll
    for (int c = 0; c < 2; ++c) {
        int idx = c * 256 + tid;
        int nr = idx >> 3, d8 = (idx & 7) * 8;
        bf16x8 v = *(const bf16x8*)&qkv[((size_t)b * 2048 + n0 + nr) * 1024 + h * 64 + d8];
        int g = ((d8 >> 3) ^ (nr >> 3)) * 8;
        *(bf16x8*)&T[nr][g] = v;
    }
    __syncthreads();
    const size_t ob = (size_t)(b * 16 + h) * 64 * 2048;
#pragma unroll
    for (int c = 0; c < 2; ++c) {
        int idx = c * 256 + tid;
        int d = idx >> 3, n8 = (idx & 7) * 8;
        bf16x8 o;
#pragma unroll
        for (int e = 0; e < 8; ++e) {
            int row = n8 + e;
            o[e] = T[row][((d >> 3) ^ (row >> 3)) * 8 + (d & 7)];
        }
        *(bf16x8*)&vT[ob + (size_t)d * 2048 + n0 + n8] = o;
    }
}

// ---------------- GEMM (unchanged, known-good) ----------------
template <bool OUT_BF16>
__global__ __launch_bounds__(256) void gemm_bt(const unsigned short* __restrict__ A,
                                               const unsigned short* __restrict__ Bt,
                                               void* __restrict__ Cout,
                                               const float* __restrict__ bias) {
    constexpr int K = 1024, NN = 1024;
    __shared__ unsigned short As[128][72];
    __shared__ unsigned short Bs[128][72];
    const int tid  = threadIdx.x;
    const int lane = tid & 63, wid = tid >> 6;
    const int wm = wid >> 1, wn = wid & 1;
    const int i = lane & 15, q8 = (lane >> 4) * 8;
    const int tm = blockIdx.y * 128, tn = blockIdx.x * 128;
    const int srow = tid >> 3, scol = (tid & 7) * 8;

    f32x4 acc[4][4] = {};

    for (int k0 = 0; k0 < K; k0 += 64) {
#pragma unroll
        for (int c = 0; c < 4; ++c) {
            int row = c * 32 + srow;
            u16x8 av = *(const u16x8*)&A [(size_t)(tm + row) * K + k0 + scol];
            u16x8 bv = *(const u16x8*)&Bt[(size_t)(tn + row) * K + k0 + scol];
            *(u16x8*)&As[row][scol] = av;
            *(u16x8*)&Bs[row][scol] = bv;
        }
        __syncthreads();
#pragma unroll
        for (int ks = 0; ks < 2; ++ks) {
            u16x8 af[4], bfr[4];
#pragma unroll
            for (int m = 0; m < 4; ++m) af[m]  = *(const u16x8*)&As[wm * 64 + m * 16 + i][ks * 32 + q8];
#pragma unroll
            for (int n = 0; n < 4; ++n) bfr[n] = *(const u16x8*)&Bs[wn * 64 + n * 16 + i][ks * 32 + q8];
#pragma unroll
            for (int m = 0; m < 4; ++m)
#pragma unroll
                for (int n = 0; n < 4; ++n)
                    acc[m][n] = mfma16u(af[m], bfr[n], acc[m][n]);
        }
        __syncthreads();
    }

    const int r0 = (lane >> 4) * 4;
#pragma unroll
    for (int n = 0; n < 4; ++n) {
        int col = tn + wn * 64 + n * 16 + i;
        float bv = 0.f;
        if constexpr (!OUT_BF16) bv = bias[col];
#pragma unroll
        for (int m = 0; m < 4; ++m) {
            int rowb = tm + wm * 64 + m * 16 + r0;
#pragma unroll
            for (int r = 0; r < 4; ++r) {
                if constexpr (OUT_BF16)
                    ((unsigned short*)Cout)[(size_t)(rowb + r) * NN + col] = f2bf(acc[m][n][r]);
                else
                    ((float*)Cout)[(size_t)(rowb + r) * NN + col] = acc[m][n][r] + bv;
            }
        }
    }
}

// ---- Flash attention v3: LDS-staged KV (gload_lds + src-swizzle), double buffer,
//      swapped QK^T in-register softmax, defer-rescale, QBLK=128 (32 q-rows/wave) ----
__global__ __launch_bounds__(256, 3) void flash_attn3(const __bf16* __restrict__ qkv,
                                                      const __bf16* __restrict__ vT,
                                                      __bf16* __restrict__ attnout) {
    __shared__ __bf16 Ks[2][4096];     // [64 kv-rows][64 d], granule^=(row&7)
    __shared__ __bf16 Vs[2][4096];     // [64 d-rows][64 kv], granule^=(row&7)
    __shared__ __bf16 Pl[4][32][64];   // per-wave P [q][k], 4-elem chunk XOR swizzle

    const int tid = threadIdx.x, lane = tid & 63, wid = tid >> 6;
    const int i = lane & 15, qg = lane >> 4;

    // XCD-aware decode: XCD j gets whole heads, q-tiles consecutive on one XCD
    const int n = blockIdx.x;                 // 0..1023
    const int j = n & 7, t = n >> 3;
    const int head = j * 8 + (t >> 4);        // 0..63
    const int b = head >> 4, h = head & 15;
    const int q0 = (t & 15) * 128;

    const size_t base  = (size_t)b * (2048 * 1024) + (size_t)h * 64;
    const size_t vbase = (size_t)head * (64 * 2048);

    // Q fragments: 2 groups of 16 q-rows
    bf16x8 qf[2][2];
#pragma unroll
    for (int g = 0; g < 2; ++g) {
        int qrow = q0 + wid * 32 + g * 16 + i;
#pragma unroll
        for (int s = 0; s < 2; ++s)
            qf[g][s] = *(const bf16x8*)&qkv[base + (size_t)qrow * 1024 + s * 32 + qg * 8];
    }

    // staging source pointers (per-lane, pre-swizzled granule)
    const int r0s = tid >> 3, g0s = tid & 7;
    const __bf16* ksrc0 = &qkv[base + (size_t)r0s * 1024 + (size_t)((g0s ^ (r0s & 7)) * 8)];
    const __bf16* ksrc1 = ksrc0 + 32 * 1024;              // rows +32 (granule unchanged mod 8)
    const __bf16* vsrc0 = &vT[vbase + (size_t)r0s * 2048 + (size_t)((g0s ^ (r0s & 7)) * 8)];
    const __bf16* vsrc1 = vsrc0 + 32 * 2048;

    auto STAGE = [&](int buf) {
        gload16(ksrc0, &Ks[buf][wid * 512]);
        gload16(ksrc1, &Ks[buf][2048 + wid * 512]);
        gload16(vsrc0, &Vs[buf][wid * 512]);
        gload16(vsrc1, &Vs[buf][2048 + wid * 512]);
        ksrc0 += 64 * 1024; ksrc1 += 64 * 1024;           // next 64 kv rows
        vsrc0 += 64;        vsrc1 += 64;                  // next 64 kv cols
    };

    float m_run[2] = {-1e30f, -1e30f}, l_run[2] = {0.f, 0.f};
    f32x4 po[2][4] = {};
    const int xsw = ((i & 7) << 1) ^ ((i >> 3) << 3);     // Pl chunk swizzle

    STAGE(0);
    __syncthreads();
    int cur = 0;

    for (int kt = 0; kt < 32; ++kt) {
        if (kt < 31) STAGE(cur ^ 1);                      // prefetch next tile (drained at barrier)
        const __bf16* Kb = Ks[cur];
        const __bf16* Vb = Vs[cur];

        // K fragments (shared by both q-groups): 8 x ds_read_b128, conflict-free
        bf16x8 kf[4][2];
#pragma unroll
        for (int m = 0; m < 4; ++m)
#pragma unroll
            for (int s = 0; s < 2; ++s)
                kf[m][s] = *(const bf16x8*)&Kb[(m * 16 + i) * 64 + ((s * 4 + qg) ^ (i & 7)) * 8];

#pragma unroll
        for (int g = 0; g < 2; ++g) {
            // S^T = K Q^T : lane holds k = m*16+qg*4+r, q-col = i
            f32x4 st[4];
#pragma unroll
            for (int m = 0; m < 4; ++m) {
                f32x4 z = {};
                z = mfma16(kf[m][0], qf[g][0], z);
                st[m] = mfma16(kf[m][1], qf[g][1], z);
            }
            float rm = fmaxf(fmaxf(fmaxf(st[0][0], st[0][1]), fmaxf(st[0][2], st[0][3])),
                             fmaxf(fmaxf(st[1][0], st[1][1]), fmaxf(st[1][2], st[1][3])));
            rm = fmaxf(rm, fmaxf(fmaxf(fmaxf(st[2][0], st[2][1]), fmaxf(st[2][2], st[2][3])),
                                 fmaxf(fmaxf(st[3][0], st[3][1]), fmaxf(st[3][2], st[3][3]))));
            rm = fmaxf(rm, __shfl_xor(rm, 16));
            rm = fmaxf(rm, __shfl_xor(rm, 32));

            float msc;
            if (__ballot(rm > m_run[g] + 64.f)) {         // rescale path (rare after warmup)
                float mnew = fmaxf(m_run[g], rm);
                msc = mnew * 0.125f;
                float alpha = __expf(fmaf(m_run[g], 0.125f, -msc));
                m_run[g] = mnew;
                l_run[g] *= alpha;
                float ar[4];
#pragma unroll
                for (int r = 0; r < 4; ++r) ar[r] = __shfl(alpha, qg * 4 + r);
#pragma unroll
                for (int nf = 0; nf < 4; ++nf) {
                    po[g][nf][0] *= ar[0]; po[g][nf][1] *= ar[1];
                    po[g][nf][2] *= ar[2]; po[g][nf][3] *= ar[3];
                }
            } else {
                msc = m_run[g] * 0.125f;                  // defer: P bounded by e^8
            }

            f32x4 psum4 = {};
#pragma unroll
            for (int m = 0; m < 4; ++m) {
                f32x4 p;
#pragma unroll
                for (int r = 0; r < 4; ++r) p[r] = __expf(fmaf(st[m][r], 0.125f, -msc));
                psum4 += p;
                bf16x4 pk;
                pk[0] = (__bf16)p[0]; pk[1] = (__bf16)p[1];
                pk[2] = (__bf16)p[2]; pk[3] = (__bf16)p[3];
                *(bf16x4*)&Pl[wid][g * 16 + i][((m * 4 + qg) ^ xsw) * 4] = pk;
            }
            float psum = (psum4[0] + psum4[1]) + (psum4[2] + psum4[3]);
            psum += __shfl_xor(psum, 16);
            psum += __shfl_xor(psum, 32);
            l_run[g] += psum;
        }

        // cross-lane P visibility (per-wave LDS; compiler can't see the dep)
        asm volatile("s_waitcnt lgkmcnt(0)" ::: "memory");
        __builtin_amdgcn_sched_barrier(0);

        // O += P V : V fragments shared by both groups
#pragma unroll
        for (int s = 0; s < 2; ++s) {
            bf16x8 pa0 = *(const bf16x8*)&Pl[wid][ 0 + i][((s * 8 + qg * 2) ^ xsw) * 4];
            bf16x8 pa1 = *(const bf16x8*)&Pl[wid][16 + i][((s * 8 + qg * 2) ^ xsw) * 4];
#pragma unroll
            for (int nf = 0; nf < 4; ++nf) {
                bf16x8 vf = *(const bf16x8*)&Vb[(nf * 16 + i) * 64 + ((s * 4 + qg) ^ (i & 7)) * 8];
                po[0][nf] = mfma16(pa0, vf, po[0][nf]);
                po[1][nf] = mfma16(pa1, vf, po[1][nf]);
            }
        }

        __syncthreads();                                  // drains vmcnt(0): prefetch landed
        cur ^= 1;
    }

    // epilogue: normalize rows and store bf16
#pragma unroll
    for (int g = 0; g < 2; ++g) {
        float linv[4];
#pragma unroll
        for (int r = 0; r < 4; ++r) linv[r] = __builtin_amdgcn_rcpf(__shfl(l_run[g], qg * 4 + r));
#pragma unroll
        for (int nf = 0; nf < 4; ++nf)
#pragma unroll
            for (int r = 0; r < 4; ++r) {
                int row = q0 + wid * 32 + g * 16 + qg * 4 + r;
                attnout[base + (size_t)row * 1024 + nf * 16 + i] = (__bf16)(po[g][nf][r] * linv[r]);
            }
    }
}

extern "C" void kernel_launch(void* const* d_in, const int* in_sizes, int n_in,
                              void* d_out, int out_size, void* d_ws, size_t ws_size,
                              hipStream_t stream) {
    const float* x    = (const float*)d_in[0];
    const float* Wqkv = (const float*)d_in[1];
    const float* Wout = (const float*)d_in[2];
    const float* bout = (const float*)d_in[3];
    float* out = (float*)d_out;

    char* ws = (char*)d_ws;
    unsigned short* xb   = (unsigned short*)(ws);            // 16M: x bf16 -> reused as vT
    unsigned short* qkvb = (unsigned short*)(ws + (16u << 20));
    unsigned short* aout = (unsigned short*)(ws + (32u << 20));
    __bf16*         wqt  = (__bf16*)(ws + (48u << 20));
    __bf16*         wot  = (__bf16*)(ws + (50u << 20));
    __bf16*         vTp  = (__bf16*)(ws);                    // overlays xb (dead after gemm1)

    cast_bf16<<<4096, 256, 0, stream>>>(x, xb);
    cast_transpose2<<<dim3(16, 16), 256, 0, stream>>>(Wqkv, wqt);
    cast_transpose2<<<dim3(16, 16), 256, 0, stream>>>(Wout, wot);

    gemm_bt<true><<<dim3(8, 64), 256, 0, stream>>>(xb, (const unsigned short*)wqt, qkvb, nullptr);

    transpose_v<<<dim3(32, 16, 4), 256, 0, stream>>>((const __bf16*)qkvb, vTp);

    flash_attn3<<<1024, 256, 0, stream>>>((const __bf16*)qkvb, vTp, (__bf16*)aout);

    gemm_bt<false><<<dim3(8, 64), 256, 0, stream>>>(aout, (const unsigned short*)wot, out, bout);
}

// Round 4
// 166.919 us; speedup vs baseline: 3.1714x; 1.1326x over previous
//
#include <hip/hip_runtime.h>

typedef float  f32x4  __attribute__((ext_vector_type(4)));
typedef __bf16 bf16x8 __attribute__((ext_vector_type(8)));
typedef __bf16 bf16x4 __attribute__((ext_vector_type(4)));
typedef unsigned short u16x8 __attribute__((ext_vector_type(8)));

__device__ __forceinline__ unsigned short f2bf(float f) {
    unsigned u = __builtin_bit_cast(unsigned, f);
    unsigned r = u + 0x7FFFu + ((u >> 16) & 1u);   // round-to-nearest-even
    return (unsigned short)(r >> 16);
}

__device__ __forceinline__ f32x4 mfma16(bf16x8 a, bf16x8 b, f32x4 c) {
    return __builtin_amdgcn_mfma_f32_16x16x32_bf16(a, b, c, 0, 0, 0);
}
__device__ __forceinline__ f32x4 mfma16u(u16x8 a, u16x8 b, f32x4 c) {
    return __builtin_amdgcn_mfma_f32_16x16x32_bf16(
        __builtin_bit_cast(bf16x8, a), __builtin_bit_cast(bf16x8, b), c, 0, 0, 0);
}

// raw 2^x (one v_exp_f32; schedulable, pure)
__device__ __forceinline__ float fexp2(float x) {
    float r;
    asm("v_exp_f32 %0, %1" : "=v"(r) : "v"(x));
    return r;
}

// async global->LDS, 16B per lane, dest = wave-uniform base + lane*16
__device__ __forceinline__ void gload16(const void* g, void* l) {
    __builtin_amdgcn_global_load_lds((const __attribute__((address_space(1))) void*)g,
                                     (__attribute__((address_space(3))) void*)l,
                                     16, 0, 0);
}

// ---------------- cast fp32 -> bf16 (8 elems / thread) ----------------
__global__ __launch_bounds__(256) void cast_bf16(const float* __restrict__ in,
                                                 unsigned short* __restrict__ out) {
    int t = blockIdx.x * 256 + threadIdx.x;
    const float* p = in + (size_t)t * 8;
    f32x4 a = *(const f32x4*)p;
    f32x4 b = *(const f32x4*)(p + 4);
    u16x8 o;
    o[0] = f2bf(a[0]); o[1] = f2bf(a[1]); o[2] = f2bf(a[2]); o[3] = f2bf(a[3]);
    o[4] = f2bf(b[0]); o[5] = f2bf(b[1]); o[6] = f2bf(b[2]); o[7] = f2bf(b[3]);
    *(u16x8*)(out + (size_t)t * 8) = o;
}

// ---- cast + transpose 1024x1024 fp32 W[k][n] -> bf16 Wt[n][k], LDS tiled ----
__global__ __launch_bounds__(256) void cast_transpose2(const float* __restrict__ W,
                                                       __bf16* __restrict__ Wt) {
    __shared__ __bf16 T[64][64];
    const int tid = threadIdx.x;
    const int k0 = blockIdx.y * 64, n0 = blockIdx.x * 64;
#pragma unroll
    for (int c = 0; c < 4; ++c) {
        int idx = c * 256 + tid;
        int kr = idx >> 4, nc = (idx & 15) * 4;
        f32x4 w = *(const f32x4*)&W[(size_t)(k0 + kr) * 1024 + n0 + nc];
        int g = ((nc >> 3) ^ (kr >> 3)) * 8 + (nc & 7);
        bf16x4 pk;
        pk[0] = (__bf16)w[0]; pk[1] = (__bf16)w[1];
        pk[2] = (__bf16)w[2]; pk[3] = (__bf16)w[3];
        *(bf16x4*)&T[kr][g] = pk;
    }
    __syncthreads();
#pragma unroll
    for (int c = 0; c < 2; ++c) {
        int idx = c * 256 + tid;
        int n = idx >> 3, k8 = (idx & 7) * 8;
        bf16x8 o;
#pragma unroll
        for (int e = 0; e < 8; ++e) {
            int k = k8 + e;
            o[e] = T[k][((n >> 3) ^ (k >> 3)) * 8 + (n & 7)];
        }
        *(bf16x8*)&Wt[(size_t)(n0 + n) * 1024 + k0 + k8] = o;
    }
}

// ---- per-head transpose: qkv[b][n][h*64+d] -> vT[(b*16+h)][d][n] ----
__global__ __launch_bounds__(256) void transpose_v(const __bf16* __restrict__ qkv,
                                                   __bf16* __restrict__ vT) {
    __shared__ __bf16 T[64][64];
    const int tid = threadIdx.x;
    const int b = blockIdx.z, h = blockIdx.y, n0 = blockIdx.x * 64;
#pragma unroll
    for (int c = 0; c < 2; ++c) {
        int idx = c * 256 + tid;
        int nr = idx >> 3, d8 = (idx & 7) * 8;
        bf16x8 v = *(const bf16x8*)&qkv[((size_t)b * 2048 + n0 + nr) * 1024 + h * 64 + d8];
        int g = ((d8 >> 3) ^ (nr >> 3)) * 8;
        *(bf16x8*)&T[nr][g] = v;
    }
    __syncthreads();
    const size_t ob = (size_t)(b * 16 + h) * 64 * 2048;
#pragma unroll
    for (int c = 0; c < 2; ++c) {
        int idx = c * 256 + tid;
        int d = idx >> 3, n8 = (idx & 7) * 8;
        bf16x8 o;
#pragma unroll
        for (int e = 0; e < 8; ++e) {
            int row = n8 + e;
            o[e] = T[row][((d >> 3) ^ (row >> 3)) * 8 + (d & 7)];
        }
        *(bf16x8*)&vT[ob + (size_t)d * 2048 + n0 + n8] = o;
    }
}

// ---------------- GEMM (unchanged, known-good) ----------------
template <bool OUT_BF16>
__global__ __launch_bounds__(256) void gemm_bt(const unsigned short* __restrict__ A,
                                               const unsigned short* __restrict__ Bt,
                                               void* __restrict__ Cout,
                                               const float* __restrict__ bias) {
    constexpr int K = 1024, NN = 1024;
    __shared__ unsigned short As[128][72];
    __shared__ unsigned short Bs[128][72];
    const int tid  = threadIdx.x;
    const int lane = tid & 63, wid = tid >> 6;
    const int wm = wid >> 1, wn = wid & 1;
    const int i = lane & 15, q8 = (lane >> 4) * 8;
    const int tm = blockIdx.y * 128, tn = blockIdx.x * 128;
    const int srow = tid >> 3, scol = (tid & 7) * 8;

    f32x4 acc[4][4] = {};

    for (int k0 = 0; k0 < K; k0 += 64) {
#pragma unroll
        for (int c = 0; c < 4; ++c) {
            int row = c * 32 + srow;
            u16x8 av = *(const u16x8*)&A [(size_t)(tm + row) * K + k0 + scol];
            u16x8 bv = *(const u16x8*)&Bt[(size_t)(tn + row) * K + k0 + scol];
            *(u16x8*)&As[row][scol] = av;
            *(u16x8*)&Bs[row][scol] = bv;
        }
        __syncthreads();
#pragma unroll
        for (int ks = 0; ks < 2; ++ks) {
            u16x8 af[4], bfr[4];
#pragma unroll
            for (int m = 0; m < 4; ++m) af[m]  = *(const u16x8*)&As[wm * 64 + m * 16 + i][ks * 32 + q8];
#pragma unroll
            for (int n = 0; n < 4; ++n) bfr[n] = *(const u16x8*)&Bs[wn * 64 + n * 16 + i][ks * 32 + q8];
#pragma unroll
            for (int m = 0; m < 4; ++m)
#pragma unroll
                for (int n = 0; n < 4; ++n)
                    acc[m][n] = mfma16u(af[m], bfr[n], acc[m][n]);
        }
        __syncthreads();
    }

    const int r0 = (lane >> 4) * 4;
#pragma unroll
    for (int n = 0; n < 4; ++n) {
        int col = tn + wn * 64 + n * 16 + i;
        float bv = 0.f;
        if constexpr (!OUT_BF16) bv = bias[col];
#pragma unroll
        for (int m = 0; m < 4; ++m) {
            int rowb = tm + wm * 64 + m * 16 + r0;
#pragma unroll
            for (int r = 0; r < 4; ++r) {
                if constexpr (OUT_BF16)
                    ((unsigned short*)Cout)[(size_t)(rowb + r) * NN + col] = f2bf(acc[m][n][r]);
                else
                    ((float*)Cout)[(size_t)(rowb + r) * NN + col] = acc[m][n][r] + bv;
            }
        }
    }
}

// ---- Flash attention v4: in-register P (k-slot permutation), no P-LDS,
//      exp2-folded softmax, l via ones-MFMA, 32KB LDS -> 4 blocks/CU ----
__global__ __launch_bounds__(256, 4) void flash_attn4(const __bf16* __restrict__ qkv,
                                                      const __bf16* __restrict__ vT,
                                                      __bf16* __restrict__ attnout) {
    __shared__ __bf16 Ks[2][4096];     // [64 kv-rows][64 d], granule ^= (row&7)
    __shared__ __bf16 Vs[2][4096];     // [64 d-rows][64 kv], granule ^= (row&7)

    const int tid = threadIdx.x, lane = tid & 63, wid = tid >> 6;
    const int i = lane & 15, qg = lane >> 4;

    // XCD-aware decode: XCD j gets whole heads
    const int n = blockIdx.x;                 // 0..1023
    const int j = n & 7, t = n >> 3;
    const int head = j * 8 + (t >> 4);        // 0..63
    const int b = head >> 4, h = head & 15;
    const int q0 = (t & 15) * 128;

    const size_t base  = (size_t)b * (2048 * 1024) + (size_t)h * 64;
    const size_t vbase = (size_t)head * (64 * 2048);

    // Q fragments: 2 groups of 16 q-rows, B-operand layout
    bf16x8 qf[2][2];
#pragma unroll
    for (int g = 0; g < 2; ++g) {
        int qrow = q0 + wid * 32 + g * 16 + i;
#pragma unroll
        for (int s = 0; s < 2; ++s)
            qf[g][s] = *(const bf16x8*)&qkv[base + (size_t)qrow * 1024 + s * 32 + qg * 8];
    }

    // staging source pointers (per-lane, pre-swizzled granule)
    const int r0s = tid >> 3, g0s = tid & 7;
    const __bf16* ksrc0 = &qkv[base + (size_t)r0s * 1024 + (size_t)((g0s ^ (r0s & 7)) * 8)];
    const __bf16* ksrc1 = ksrc0 + 32 * 1024;
    const __bf16* vsrc0 = &vT[vbase + (size_t)r0s * 2048 + (size_t)((g0s ^ (r0s & 7)) * 8)];
    const __bf16* vsrc1 = vsrc0 + 32 * 2048;

    auto STAGE = [&](int buf) {
        gload16(ksrc0, &Ks[buf][wid * 512]);
        gload16(ksrc1, &Ks[buf][2048 + wid * 512]);
        gload16(vsrc0, &Vs[buf][wid * 512]);
        gload16(vsrc1, &Vs[buf][2048 + wid * 512]);
        ksrc0 += 64 * 1024; ksrc1 += 64 * 1024;
        vsrc0 += 64;        vsrc1 += 64;
    };

    const float SL2E = 0.18033688f;           // 0.125 * log2(e)
    float m_run[2] = {-1e30f, -1e30f};
    f32x4 po[2][4] = {};
    f32x4 po5[2]   = {};                      // row-sums l via ones-MFMA
    bf16x8 ones;
#pragma unroll
    for (int e = 0; e < 8; ++e) ones[e] = (__bf16)1.0f;

    STAGE(0);
    __syncthreads();
    int cur = 0;

    for (int kt = 0; kt < 32; ++kt) {
        if (kt < 31) STAGE(cur ^ 1);          // prefetch next tile
        const __bf16* Kb = Ks[cur];
        const __bf16* Vb = Vs[cur];

        __builtin_amdgcn_s_setprio(1);
        // S^T = K Q^T, m-outer to keep kf transient (VGPR pressure)
        f32x4 st[2][4];
#pragma unroll
        for (int m = 0; m < 4; ++m) {
            bf16x8 kf0 = *(const bf16x8*)&Kb[(m * 16 + i) * 64 + ((qg) ^ (i & 7)) * 8];
            bf16x8 kf1 = *(const bf16x8*)&Kb[(m * 16 + i) * 64 + ((4 + qg) ^ (i & 7)) * 8];
            f32x4 z0 = {}, z1 = {};
            z0 = mfma16(kf0, qf[0][0], z0);
            st[0][m] = mfma16(kf1, qf[0][1], z0);
            z1 = mfma16(kf0, qf[1][0], z1);
            st[1][m] = mfma16(kf1, qf[1][1], z1);
        }
        __builtin_amdgcn_s_setprio(0);

        // softmax per q-group; P stays in registers (k-slot permutation)
        bf16x8 pa[2][2];
#pragma unroll
        for (int g = 0; g < 2; ++g) {
            float rm = fmaxf(fmaxf(fmaxf(st[g][0][0], st[g][0][1]), st[g][0][2]),
                       fmaxf(fmaxf(st[g][0][3], st[g][1][0]), st[g][1][1]));
            rm = fmaxf(rm, fmaxf(fmaxf(fmaxf(st[g][1][2], st[g][1][3]), st[g][2][0]),
                           fmaxf(fmaxf(st[g][2][1], st[g][2][2]), st[g][2][3])));
            rm = fmaxf(rm, fmaxf(fmaxf(st[g][3][0], st[g][3][1]),
                                 fmaxf(st[g][3][2], st[g][3][3])));
            rm = fmaxf(rm, __shfl_xor(rm, 16));
            rm = fmaxf(rm, __shfl_xor(rm, 32));

            if (__ballot(rm > m_run[g] + 64.f)) {          // rescale (rare)
                float mnew  = fmaxf(m_run[g], rm);
                float alpha = fexp2((m_run[g] - mnew) * SL2E);
                m_run[g] = mnew;
                float ar[4];
#pragma unroll
                for (int r = 0; r < 4; ++r) ar[r] = __shfl(alpha, qg * 4 + r);
#pragma unroll
                for (int nf = 0; nf < 4; ++nf) {
                    po[g][nf][0] *= ar[0]; po[g][nf][1] *= ar[1];
                    po[g][nf][2] *= ar[2]; po[g][nf][3] *= ar[3];
                }
                po5[g][0] *= ar[0]; po5[g][1] *= ar[1];
                po5[g][2] *= ar[2]; po5[g][3] *= ar[3];
            }
            float msc = m_run[g] * SL2E;

#pragma unroll
            for (int m = 0; m < 4; ++m)
#pragma unroll
                for (int r = 0; r < 4; ++r)
                    st[g][m][r] = fexp2(fmaf(st[g][m][r], SL2E, -msc));

            // A-fragment in place: slot (s,e) <- st[2s + (e>>2)][e&3]
#pragma unroll
            for (int r = 0; r < 4; ++r) {
                pa[g][0][r]     = (__bf16)st[g][0][r];
                pa[g][0][4 + r] = (__bf16)st[g][1][r];
                pa[g][1][r]     = (__bf16)st[g][2][r];
                pa[g][1][4 + r] = (__bf16)st[g][3][r];
            }
        }

        // O += P V  (B reads LDS at the matching k-slot permutation)
        __builtin_amdgcn_s_setprio(1);
#pragma unroll
        for (int s = 0; s < 2; ++s) {
#pragma unroll
            for (int nf = 0; nf < 4; ++nf) {
                const int row = nf * 16 + i;
                bf16x8 vf;
                *(bf16x4*)&vf = *(const bf16x4*)
                    &Vb[row * 64 + (((s * 4 + (qg >> 1)) ^ (i & 7)) * 8 + (qg & 1) * 4)];
                *((bf16x4*)&vf + 1) = *(const bf16x4*)
                    &Vb[row * 64 + (((s * 4 + 2 + (qg >> 1)) ^ (i & 7)) * 8 + (qg & 1) * 4)];
                po[0][nf] = mfma16(pa[0][s], vf, po[0][nf]);
                po[1][nf] = mfma16(pa[1][s], vf, po[1][nf]);
            }
            po5[0] = mfma16(pa[0][s], ones, po5[0]);
            po5[1] = mfma16(pa[1][s], ones, po5[1]);
        }
        __builtin_amdgcn_s_setprio(0);

        __syncthreads();                                   // prefetch landed
        cur ^= 1;
    }

    // epilogue: l is in po5 (all columns identical) — no shuffles
#pragma unroll
    for (int g = 0; g < 2; ++g) {
        float linv[4];
#pragma unroll
        for (int r = 0; r < 4; ++r) linv[r] = __builtin_amdgcn_rcpf(po5[g][r]);
#pragma unroll
        for (int nf = 0; nf < 4; ++nf)
#pragma unroll
            for (int r = 0; r < 4; ++r) {
                int row = q0 + wid * 32 + g * 16 + qg * 4 + r;
                attnout[base + (size_t)row * 1024 + nf * 16 + i] = (__bf16)(po[g][nf][r] * linv[r]);
            }
    }
}

extern "C" void kernel_launch(void* const* d_in, const int* in_sizes, int n_in,
                              void* d_out, int out_size, void* d_ws, size_t ws_size,
                              hipStream_t stream) {
    const float* x    = (const float*)d_in[0];
    const float* Wqkv = (const float*)d_in[1];
    const float* Wout = (const float*)d_in[2];
    const float* bout = (const float*)d_in[3];
    float* out = (float*)d_out;

    char* ws = (char*)d_ws;
    unsigned short* xb   = (unsigned short*)(ws);            // 16M: x bf16 -> reused as vT
    unsigned short* qkvb = (unsigned short*)(ws + (16u << 20));
    unsigned short* aout = (unsigned short*)(ws + (32u << 20));
    __bf16*         wqt  = (__bf16*)(ws + (48u << 20));
    __bf16*         wot  = (__bf16*)(ws + (50u << 20));
    __bf16*         vTp  = (__bf16*)(ws);                    // overlays xb (dead after gemm1)

    cast_bf16<<<4096, 256, 0, stream>>>(x, xb);
    cast_transpose2<<<dim3(16, 16), 256, 0, stream>>>(Wqkv, wqt);
    cast_transpose2<<<dim3(16, 16), 256, 0, stream>>>(Wout, wot);

    gemm_bt<true><<<dim3(8, 64), 256, 0, stream>>>(xb, (const unsigned short*)wqt, qkvb, nullptr);

    transpose_v<<<dim3(32, 16, 4), 256, 0, stream>>>((const __bf16*)qkvb, vTp);

    flash_attn4<<<1024, 256, 0, stream>>>((const __bf16*)qkvb, vTp, (__bf16*)aout);

    gemm_bt<false><<<dim3(8, 64), 256, 0, stream>>>(aout, (const unsigned short*)wot, out, bout);
}

// Round 6
// 161.326 us; speedup vs baseline: 3.2814x; 1.0347x over previous
//
#include <hip/hip_runtime.h>

typedef float  f32x4  __attribute__((ext_vector_type(4)));
typedef __bf16 bf16x8 __attribute__((ext_vector_type(8)));
typedef __bf16 bf16x4 __attribute__((ext_vector_type(4)));
typedef unsigned short u16x8 __attribute__((ext_vector_type(8)));

__device__ __forceinline__ unsigned short f2bf(float f) {
    unsigned u = __builtin_bit_cast(unsigned, f);
    unsigned r = u + 0x7FFFu + ((u >> 16) & 1u);   // round-to-nearest-even
    return (unsigned short)(r >> 16);
}

__device__ __forceinline__ f32x4 mfma16(bf16x8 a, bf16x8 b, f32x4 c) {
    return __builtin_amdgcn_mfma_f32_16x16x32_bf16(a, b, c, 0, 0, 0);
}
__device__ __forceinline__ f32x4 mfma16u(u16x8 a, u16x8 b, f32x4 c) {
    return __builtin_amdgcn_mfma_f32_16x16x32_bf16(
        __builtin_bit_cast(bf16x8, a), __builtin_bit_cast(bf16x8, b), c, 0, 0, 0);
}

__device__ __forceinline__ float fexp2(float x) {
    float r;
    asm("v_exp_f32 %0, %1" : "=v"(r) : "v"(x));
    return r;
}

// async global->LDS, 16B per lane, dest = wave-uniform base + lane*16
__device__ __forceinline__ void gload16(const void* g, void* l) {
    __builtin_amdgcn_global_load_lds((const __attribute__((address_space(1))) void*)g,
                                     (__attribute__((address_space(3))) void*)l,
                                     16, 0, 0);
}

// ---------------- cast fp32 -> bf16 (8 elems / thread) ----------------
__global__ __launch_bounds__(256) void cast_bf16(const float* __restrict__ in,
                                                 unsigned short* __restrict__ out) {
    int t = blockIdx.x * 256 + threadIdx.x;
    const float* p = in + (size_t)t * 8;
    f32x4 a = *(const f32x4*)p;
    f32x4 b = *(const f32x4*)(p + 4);
    u16x8 o;
    o[0] = f2bf(a[0]); o[1] = f2bf(a[1]); o[2] = f2bf(a[2]); o[3] = f2bf(a[3]);
    o[4] = f2bf(b[0]); o[5] = f2bf(b[1]); o[6] = f2bf(b[2]); o[7] = f2bf(b[3]);
    *(u16x8*)(out + (size_t)t * 8) = o;
}

// ---- cast + transpose both 1024x1024 weights: W[k][n] -> bf16 Wt[n][k] ----
__global__ __launch_bounds__(256) void cast_transpose2(const float* __restrict__ W0,
                                                       const float* __restrict__ W1,
                                                       __bf16* __restrict__ T0Q,
                                                       __bf16* __restrict__ T1Q) {
    const float* W = blockIdx.z ? W1 : W0;
    __bf16* Wt = blockIdx.z ? T1Q : T0Q;
    __shared__ __bf16 T[64][64];
    const int tid = threadIdx.x;
    const int k0 = blockIdx.y * 64, n0 = blockIdx.x * 64;
#pragma unroll
    for (int c = 0; c < 4; ++c) {
        int idx = c * 256 + tid;
        int kr = idx >> 4, nc = (idx & 15) * 4;
        f32x4 w = *(const f32x4*)&W[(size_t)(k0 + kr) * 1024 + n0 + nc];
        int g = ((nc >> 3) ^ (kr >> 3)) * 8 + (nc & 7);
        bf16x4 pk;
        pk[0] = (__bf16)w[0]; pk[1] = (__bf16)w[1];
        pk[2] = (__bf16)w[2]; pk[3] = (__bf16)w[3];
        *(bf16x4*)&T[kr][g] = pk;
    }
    __syncthreads();
#pragma unroll
    for (int c = 0; c < 2; ++c) {
        int idx = c * 256 + tid;
        int n = idx >> 3, k8 = (idx & 7) * 8;
        bf16x8 o;
#pragma unroll
        for (int e = 0; e < 8; ++e) {
            int k = k8 + e;
            o[e] = T[k][((n >> 3) ^ (k >> 3)) * 8 + (n & 7)];
        }
        *(bf16x8*)&Wt[(size_t)(n0 + n) * 1024 + k0 + k8] = o;
    }
}

// ---- per-head transpose: qkv[b][n][h*64+d] -> vT[(b*16+h)][d][n] ----
__global__ __launch_bounds__(256) void transpose_v(const __bf16* __restrict__ qkv,
                                                   __bf16* __restrict__ vT) {
    __shared__ __bf16 T[64][64];
    const int tid = threadIdx.x;
    const int b = blockIdx.z, h = blockIdx.y, n0 = blockIdx.x * 64;
#pragma unroll
    for (int c = 0; c < 2; ++c) {
        int idx = c * 256 + tid;
        int nr = idx >> 3, d8 = (idx & 7) * 8;
        bf16x8 v = *(const bf16x8*)&qkv[((size_t)b * 2048 + n0 + nr) * 1024 + h * 64 + d8];
        int g = ((d8 >> 3) ^ (nr >> 3)) * 8;
        *(bf16x8*)&T[nr][g] = v;
    }
    __syncthreads();
    const size_t ob = (size_t)(b * 16 + h) * 64 * 2048;
#pragma unroll
    for (int c = 0; c < 2; ++c) {
        int idx = c * 256 + tid;
        int d = idx >> 3, n8 = (idx & 7) * 8;
        bf16x8 o;
#pragma unroll
        for (int e = 0; e < 8; ++e) {
            int row = n8 + e;
            o[e] = T[row][((d >> 3) ^ (row >> 3)) * 8 + (d & 7)];
        }
        *(bf16x8*)&vT[ob + (size_t)d * 2048 + n0 + n8] = o;
    }
}

// ---------------- GEMM (round-1 structure + bijective XCD swizzle) ----------------
template <bool OUT_BF16>
__global__ __launch_bounds__(256) void gemm_bt(const unsigned short* __restrict__ A,
                                               const unsigned short* __restrict__ Bt,
                                               void* __restrict__ Cout,
                                               const float* __restrict__ bias) {
    constexpr int K = 1024, NN = 1024;
    __shared__ unsigned short As[128][72];
    __shared__ unsigned short Bs[128][72];
    const int tid  = threadIdx.x;
    const int lane = tid & 63, wid = tid >> 6;
    const int wm = wid >> 1, wn = wid & 1;
    const int i = lane & 15, q8 = (lane >> 4) * 8;
    // XCD-aware: 512 blocks (8x64), 512%8==0 -> bijective swizzle;
    // XCD j gets an 8(M)x8(N) tile band -> A-band + B-panel L2-resident
    const int bid = blockIdx.y * 8 + blockIdx.x;
    const int swz = (bid & 7) * 64 + (bid >> 3);
    const int tm = (swz >> 3) * 128, tn = (swz & 7) * 128;
    const int srow = tid >> 3, scol = (tid & 7) * 8;

    f32x4 acc[4][4] = {};

    for (int k0 = 0; k0 < K; k0 += 64) {
#pragma unroll
        for (int c = 0; c < 4; ++c) {
            int row = c * 32 + srow;
            u16x8 av = *(const u16x8*)&A [(size_t)(tm + row) * K + k0 + scol];
            u16x8 bv = *(const u16x8*)&Bt[(size_t)(tn + row) * K + k0 + scol];
            *(u16x8*)&As[row][scol] = av;
            *(u16x8*)&Bs[row][scol] = bv;
        }
        __syncthreads();
#pragma unroll
        for (int ks = 0; ks < 2; ++ks) {
            u16x8 af[4], bfr[4];
#pragma unroll
            for (int m = 0; m < 4; ++m) af[m]  = *(const u16x8*)&As[wm * 64 + m * 16 + i][ks * 32 + q8];
#pragma unroll
            for (int nn = 0; nn < 4; ++nn) bfr[nn] = *(const u16x8*)&Bs[wn * 64 + nn * 16 + i][ks * 32 + q8];
#pragma unroll
            for (int m = 0; m < 4; ++m)
#pragma unroll
                for (int nn = 0; nn < 4; ++nn)
                    acc[m][nn] = mfma16u(af[m], bfr[nn], acc[m][nn]);
        }
        __syncthreads();
    }

    const int r0 = (lane >> 4) * 4;
#pragma unroll
    for (int nn = 0; nn < 4; ++nn) {
        int col = tn + wn * 64 + nn * 16 + i;
        float bv = 0.f;
        if constexpr (!OUT_BF16) bv = bias[col];
#pragma unroll
        for (int m = 0; m < 4; ++m) {
            int rowb = tm + wm * 64 + m * 16 + r0;
#pragma unroll
            for (int r = 0; r < 4; ++r) {
                if constexpr (OUT_BF16)
                    ((unsigned short*)Cout)[(size_t)(rowb + r) * NN + col] = f2bf(acc[m][nn][r]);
                else
                    ((float*)Cout)[(size_t)(rowb + r) * NN + col] = acc[m][nn][r] + bv;
            }
        }
    }
}

// ---- Flash attention v4 (known-good) + shfl-free softmax common path ----
__global__ __launch_bounds__(256, 4) void flash_attn4(const __bf16* __restrict__ qkv,
                                                      const __bf16* __restrict__ vT,
                                                      __bf16* __restrict__ attnout) {
    __shared__ __bf16 Ks[2][4096];     // [64 kv-rows][64 d], granule ^= (row&7)
    __shared__ __bf16 Vs[2][4096];     // [64 d-rows][64 kv], granule ^= (row&7)

    const int tid = threadIdx.x, lane = tid & 63, wid = tid >> 6;
    const int i = lane & 15, qg = lane >> 4;

    // XCD-aware decode: XCD j gets whole heads
    const int n = blockIdx.x;                 // 0..1023
    const int j = n & 7, t = n >> 3;
    const int head = j * 8 + (t >> 4);        // 0..63
    const int b = head >> 4, h = head & 15;
    const int q0 = (t & 15) * 128;

    const size_t base  = (size_t)b * (2048 * 1024) + (size_t)h * 64;
    const size_t vbase = (size_t)head * (64 * 2048);

    // Q fragments: 2 groups of 16 q-rows, B-operand layout
    bf16x8 qf[2][2];
#pragma unroll
    for (int g = 0; g < 2; ++g) {
        int qrow = q0 + wid * 32 + g * 16 + i;
#pragma unroll
        for (int s = 0; s < 2; ++s)
            qf[g][s] = *(const bf16x8*)&qkv[base + (size_t)qrow * 1024 + s * 32 + qg * 8];
    }

    // staging source pointers (per-lane, pre-swizzled granule)
    const int r0s = tid >> 3, g0s = tid & 7;
    const __bf16* ksrc0 = &qkv[base + (size_t)r0s * 1024 + (size_t)((g0s ^ (r0s & 7)) * 8)];
    const __bf16* ksrc1 = ksrc0 + 32 * 1024;
    const __bf16* vsrc0 = &vT[vbase + (size_t)r0s * 2048 + (size_t)((g0s ^ (r0s & 7)) * 8)];
    const __bf16* vsrc1 = vsrc0 + 32 * 2048;

    auto STAGE = [&](int buf) {
        gload16(ksrc0, &Ks[buf][wid * 512]);
        gload16(ksrc1, &Ks[buf][2048 + wid * 512]);
        gload16(vsrc0, &Vs[buf][wid * 512]);
        gload16(vsrc1, &Vs[buf][2048 + wid * 512]);
        ksrc0 += 64 * 1024; ksrc1 += 64 * 1024;
        vsrc0 += 64;        vsrc1 += 64;
    };

    const float SL2E = 0.18033688f;           // 0.125 * log2(e)
    float m_run[2] = {-1e30f, -1e30f};
    float msc[2]   = {-1e30f, -1e30f};
    f32x4 po[2][4] = {};
    f32x4 po5[2]   = {};                      // row-sums l via ones-MFMA
    bf16x8 ones;
#pragma unroll
    for (int e = 0; e < 8; ++e) ones[e] = (__bf16)1.0f;

    STAGE(0);
    __syncthreads();
    int cur = 0;

    for (int kt = 0; kt < 32; ++kt) {
        if (kt < 31) STAGE(cur ^ 1);          // prefetch next tile
        const __bf16* Kb = Ks[cur];
        const __bf16* Vb = Vs[cur];

        __builtin_amdgcn_s_setprio(1);
        // S^T = K Q^T, m-outer to keep kf transient (VGPR pressure)
        f32x4 st[2][4];
#pragma unroll
        for (int m = 0; m < 4; ++m) {
            bf16x8 kf0 = *(const bf16x8*)&Kb[(m * 16 + i) * 64 + ((qg) ^ (i & 7)) * 8];
            bf16x8 kf1 = *(const bf16x8*)&Kb[(m * 16 + i) * 64 + ((4 + qg) ^ (i & 7)) * 8];
            f32x4 z0 = {}, z1 = {};
            z0 = mfma16(kf0, qf[0][0], z0);
            st[0][m] = mfma16(kf1, qf[0][1], z0);
            z1 = mfma16(kf0, qf[1][0], z1);
            st[1][m] = mfma16(kf1, qf[1][1], z1);
        }
        __builtin_amdgcn_s_setprio(0);

        // softmax: shfl-free common path, trigger-only rescale; P stays in registers
        bf16x8 pa[2][2];
#pragma unroll
        for (int g = 0; g < 2; ++g) {
            f32x4 mv = __builtin_elementwise_max(st[g][0], st[g][1]);
            mv = __builtin_elementwise_max(mv, st[g][2]);
            mv = __builtin_elementwise_max(mv, st[g][3]);
            float rmv = fmaxf(fmaxf(mv[0], mv[1]), fmaxf(mv[2], mv[3]));

            if (__ballot(rmv > m_run[g] + 64.f)) {         // tile 0 only, in practice
                float rm = fmaxf(rmv, __shfl_xor(rmv, 16));
                rm = fmaxf(rm, __shfl_xor(rm, 32));
                float mnew  = fmaxf(m_run[g], rm);
                float alpha = fexp2(fmaf(m_run[g], SL2E, -mnew * SL2E));
                m_run[g] = mnew;
                msc[g]   = mnew * SL2E;
                float ar[4];
#pragma unroll
                for (int r = 0; r < 4; ++r) ar[r] = __shfl(alpha, qg * 4 + r);
#pragma unroll
                for (int nf = 0; nf < 4; ++nf) {
                    po[g][nf][0] *= ar[0]; po[g][nf][1] *= ar[1];
                    po[g][nf][2] *= ar[2]; po[g][nf][3] *= ar[3];
                }
                po5[g][0] *= ar[0]; po5[g][1] *= ar[1];
                po5[g][2] *= ar[2]; po5[g][3] *= ar[3];
            }

#pragma unroll
            for (int m = 0; m < 4; ++m)
#pragma unroll
                for (int r = 0; r < 4; ++r)
                    st[g][m][r] = fexp2(fmaf(st[g][m][r], SL2E, -msc[g]));

            // A-fragment in place: slot (s,e) <- st[2s + (e>>2)][e&3]
#pragma unroll
            for (int r = 0; r < 4; ++r) {
                pa[g][0][r]     = (__bf16)st[g][0][r];
                pa[g][0][4 + r] = (__bf16)st[g][1][r];
                pa[g][1][r]     = (__bf16)st[g][2][r];
                pa[g][1][4 + r] = (__bf16)st[g][3][r];
            }
        }

        // O += P V  (B reads LDS at the matching k-slot permutation)
        __builtin_amdgcn_s_setprio(1);
#pragma unroll
        for (int s = 0; s < 2; ++s) {
#pragma unroll
            for (int nf = 0; nf < 4; ++nf) {
                const int row = nf * 16 + i;
                bf16x8 vf;
                *(bf16x4*)&vf = *(const bf16x4*)
                    &Vb[row * 64 + (((s * 4 + (qg >> 1)) ^ (i & 7)) * 8 + (qg & 1) * 4)];
                *((bf16x4*)&vf + 1) = *(const bf16x4*)
                    &Vb[row * 64 + (((s * 4 + 2 + (qg >> 1)) ^ (i & 7)) * 8 + (qg & 1) * 4)];
                po[0][nf] = mfma16(pa[0][s], vf, po[0][nf]);
                po[1][nf] = mfma16(pa[1][s], vf, po[1][nf]);
            }
            po5[0] = mfma16(pa[0][s], ones, po5[0]);
            po5[1] = mfma16(pa[1][s], ones, po5[1]);
        }
        __builtin_amdgcn_s_setprio(0);

        __syncthreads();                                   // prefetch landed
        cur ^= 1;
    }

    // epilogue: l is in po5 (all q-columns identical) — no shuffles
#pragma unroll
    for (int g = 0; g < 2; ++g) {
        float linv[4];
#pragma unroll
        for (int r = 0; r < 4; ++r) linv[r] = __builtin_amdgcn_rcpf(po5[g][r]);
#pragma unroll
        for (int nf = 0; nf < 4; ++nf)
#pragma unroll
            for (int r = 0; r < 4; ++r) {
                int row = q0 + wid * 32 + g * 16 + qg * 4 + r;
                attnout[base + (size_t)row * 1024 + nf * 16 + i] = (__bf16)(po[g][nf][r] * linv[r]);
            }
    }
}

extern "C" void kernel_launch(void* const* d_in, const int* in_sizes, int n_in,
                              void* d_out, int out_size, void* d_ws, size_t ws_size,
                              hipStream_t stream) {
    const float* x    = (const float*)d_in[0];
    const float* Wqkv = (const float*)d_in[1];
    const float* Wout = (const float*)d_in[2];
    const float* bout = (const float*)d_in[3];
    float* out = (float*)d_out;

    char* ws = (char*)d_ws;
    unsigned short* xb   = (unsigned short*)(ws);            // 16M: x bf16 -> reused as vT
    unsigned short* qkvb = (unsigned short*)(ws + (16u << 20));
    unsigned short* aout = (unsigned short*)(ws + (32u << 20));
    __bf16*         wqt  = (__bf16*)(ws + (48u << 20));
    __bf16*         wot  = (__bf16*)(ws + (50u << 20));
    __bf16*         vTp  = (__bf16*)(ws);                    // overlays xb (dead after gemm1)

    cast_bf16<<<4096, 256, 0, stream>>>(x, xb);
    cast_transpose2<<<dim3(16, 16, 2), 256, 0, stream>>>(Wqkv, Wout, wqt, wot);

    gemm_bt<true><<<dim3(8, 64), 256, 0, stream>>>(xb, (const unsigned short*)wqt, qkvb, nullptr);

    transpose_v<<<dim3(32, 16, 4), 256, 0, stream>>>((const __bf16*)qkvb, vTp);

    flash_attn4<<<1024, 256, 0, stream>>>((const __bf16*)qkvb, vTp, (__bf16*)aout);

    gemm_bt<false><<<dim3(8, 64), 256, 0, stream>>>(aout, (const unsigned short*)wot, out, bout);
}

// Round 7
// 152.726 us; speedup vs baseline: 3.4662x; 1.0563x over previous
//
#include <hip/hip_runtime.h>

typedef float  f32x4  __attribute__((ext_vector_type(4)));
typedef __bf16 bf16x8 __attribute__((ext_vector_type(8)));
typedef __bf16 bf16x4 __attribute__((ext_vector_type(4)));
typedef unsigned short u16x8 __attribute__((ext_vector_type(8)));

__device__ __forceinline__ unsigned short f2bf(float f) {
    unsigned u = __builtin_bit_cast(unsigned, f);
    unsigned r = u + 0x7FFFu + ((u >> 16) & 1u);   // round-to-nearest-even
    return (unsigned short)(r >> 16);
}

__device__ __forceinline__ f32x4 mfma16(bf16x8 a, bf16x8 b, f32x4 c) {
    return __builtin_amdgcn_mfma_f32_16x16x32_bf16(a, b, c, 0, 0, 0);
}
__device__ __forceinline__ f32x4 mfma16u(u16x8 a, u16x8 b, f32x4 c) {
    return __builtin_amdgcn_mfma_f32_16x16x32_bf16(
        __builtin_bit_cast(bf16x8, a), __builtin_bit_cast(bf16x8, b), c, 0, 0, 0);
}

__device__ __forceinline__ float fexp2(float x) {
    float r;
    asm("v_exp_f32 %0, %1" : "=v"(r) : "v"(x));
    return r;
}

// async global->LDS, 16B per lane, dest = wave-uniform base + lane*16
__device__ __forceinline__ void gload16(const void* g, void* l) {
    __builtin_amdgcn_global_load_lds((const __attribute__((address_space(1))) void*)g,
                                     (__attribute__((address_space(3))) void*)l,
                                     16, 0, 0);
}

// ---------------- cast fp32 -> bf16 (8 elems / thread) ----------------
__global__ __launch_bounds__(256) void cast_bf16(const float* __restrict__ in,
                                                 unsigned short* __restrict__ out) {
    int t = blockIdx.x * 256 + threadIdx.x;
    const float* p = in + (size_t)t * 8;
    f32x4 a = *(const f32x4*)p;
    f32x4 b = *(const f32x4*)(p + 4);
    u16x8 o;
    o[0] = f2bf(a[0]); o[1] = f2bf(a[1]); o[2] = f2bf(a[2]); o[3] = f2bf(a[3]);
    o[4] = f2bf(b[0]); o[5] = f2bf(b[1]); o[6] = f2bf(b[2]); o[7] = f2bf(b[3]);
    *(u16x8*)(out + (size_t)t * 8) = o;
}

// ---- cast + transpose both 1024x1024 weights: W[k][n] -> bf16 Wt[n][k] ----
__global__ __launch_bounds__(256) void cast_transpose2(const float* __restrict__ W0,
                                                       const float* __restrict__ W1,
                                                       __bf16* __restrict__ T0Q,
                                                       __bf16* __restrict__ T1Q) {
    const float* W = blockIdx.z ? W1 : W0;
    __bf16* Wt = blockIdx.z ? T1Q : T0Q;
    __shared__ __bf16 T[64][64];
    const int tid = threadIdx.x;
    const int k0 = blockIdx.y * 64, n0 = blockIdx.x * 64;
#pragma unroll
    for (int c = 0; c < 4; ++c) {
        int idx = c * 256 + tid;
        int kr = idx >> 4, nc = (idx & 15) * 4;
        f32x4 w = *(const f32x4*)&W[(size_t)(k0 + kr) * 1024 + n0 + nc];
        int g = ((nc >> 3) ^ (kr >> 3)) * 8 + (nc & 7);
        bf16x4 pk;
        pk[0] = (__bf16)w[0]; pk[1] = (__bf16)w[1];
        pk[2] = (__bf16)w[2]; pk[3] = (__bf16)w[3];
        *(bf16x4*)&T[kr][g] = pk;
    }
    __syncthreads();
#pragma unroll
    for (int c = 0; c < 2; ++c) {
        int idx = c * 256 + tid;
        int n = idx >> 3, k8 = (idx & 7) * 8;
        bf16x8 o;
#pragma unroll
        for (int e = 0; e < 8; ++e) {
            int k = k8 + e;
            o[e] = T[k][((n >> 3) ^ (k >> 3)) * 8 + (n & 7)];
        }
        *(bf16x8*)&Wt[(size_t)(n0 + n) * 1024 + k0 + k8] = o;
    }
}

// ---------------- GEMM + optional fused per-head V^T epilogue ----------------
// C[8192][1024] = A[8192][1024] * Bt[1024][1024]^T.
// WRITE_VT: additionally emit vT[(b*16+h)][d][n] via LDS transpose of the C tile.
template <bool OUT_BF16, bool WRITE_VT>
__global__ __launch_bounds__(256) void gemm_bt(const unsigned short* __restrict__ A,
                                               const unsigned short* __restrict__ Bt,
                                               void* __restrict__ Cout,
                                               const float* __restrict__ bias,
                                               __bf16* __restrict__ vT) {
    constexpr int K = 1024, NN = 1024;
    __shared__ unsigned short SM[18432];            // As(128x72) | Bs(128x72); reused as T[128][128]
    typedef unsigned short u16_72[72];
    u16_72* As = (u16_72*)SM;
    u16_72* Bs = (u16_72*)(SM + 9216);
    const int tid  = threadIdx.x;
    const int lane = tid & 63, wid = tid >> 6;
    const int wm = wid >> 1, wn = wid & 1;
    const int i = lane & 15, q8 = (lane >> 4) * 8;
    // XCD-aware: 512 blocks, bijective swizzle; XCD j gets an 8x8 tile band
    const int bid = blockIdx.y * 8 + blockIdx.x;
    const int swz = (bid & 7) * 64 + (bid >> 3);
    const int tm = (swz >> 3) * 128, tn = (swz & 7) * 128;
    const int srow = tid >> 3, scol = (tid & 7) * 8;

    f32x4 acc[4][4] = {};

    for (int k0 = 0; k0 < K; k0 += 64) {
#pragma unroll
        for (int c = 0; c < 4; ++c) {
            int row = c * 32 + srow;
            u16x8 av = *(const u16x8*)&A [(size_t)(tm + row) * K + k0 + scol];
            u16x8 bv = *(const u16x8*)&Bt[(size_t)(tn + row) * K + k0 + scol];
            *(u16x8*)&As[row][scol] = av;
            *(u16x8*)&Bs[row][scol] = bv;
        }
        __syncthreads();
#pragma unroll
        for (int ks = 0; ks < 2; ++ks) {
            u16x8 af[4], bfr[4];
#pragma unroll
            for (int m = 0; m < 4; ++m) af[m]  = *(const u16x8*)&As[wm * 64 + m * 16 + i][ks * 32 + q8];
#pragma unroll
            for (int nn = 0; nn < 4; ++nn) bfr[nn] = *(const u16x8*)&Bs[wn * 64 + nn * 16 + i][ks * 32 + q8];
#pragma unroll
            for (int m = 0; m < 4; ++m)
#pragma unroll
                for (int nn = 0; nn < 4; ++nn)
                    acc[m][nn] = mfma16u(af[m], bfr[nn], acc[m][nn]);
        }
        __syncthreads();
    }

    const int r0 = (lane >> 4) * 4;
#pragma unroll
    for (int nn = 0; nn < 4; ++nn) {
        int col = tn + wn * 64 + nn * 16 + i;
        float bv = 0.f;
        if constexpr (!OUT_BF16) bv = bias[col];
#pragma unroll
        for (int m = 0; m < 4; ++m) {
            int rowb = tm + wm * 64 + m * 16 + r0;
#pragma unroll
            for (int r = 0; r < 4; ++r) {
                if constexpr (OUT_BF16)
                    ((unsigned short*)Cout)[(size_t)(rowb + r) * NN + col] = f2bf(acc[m][nn][r]);
                else
                    ((float*)Cout)[(size_t)(rowb + r) * NN + col] = acc[m][nn][r] + bv;
            }
        }
    }

    if constexpr (WRITE_VT) {
        // phase 1: acc -> granule-XOR-swizzled T[128][128] (overwrites As/Bs; all reads done)
        unsigned short* T = SM;
#pragma unroll
        for (int nn = 0; nn < 4; ++nn) {
            const int col = wn * 64 + nn * 16 + i;
            const int g = col >> 3, c7 = col & 7;
#pragma unroll
            for (int m = 0; m < 4; ++m) {
                const int rbase = wm * 64 + m * 16 + r0;        // r0..r0+3 share rbase>>3
                const int rsw = (rbase >> 3) & 15;
#pragma unroll
                for (int r = 0; r < 4; ++r)
                    T[(rbase + r) * 128 + ((g ^ rsw) * 8) + c7] = f2bf(acc[m][nn][r]);
            }
        }
        __syncthreads();
        // phase 2: coalesced 16B writes of vT[head][d][tm..tm+128)
        const size_t vb0 = ((size_t)(tm >> 11) * 16 + (tn >> 6)) * 131072 + (size_t)(tm & 2047);
#pragma unroll
        for (int c = 0; c < 8; ++c) {
            int idx = c * 256 + tid;                 // 0..2047
            int hh = idx >> 10, dd = (idx >> 4) & 63, n8 = (idx & 15) * 8;
            int g = (hh * 64 + dd) >> 3, c7 = dd & 7, rsw = idx & 15;
            u16x8 o;
#pragma unroll
            for (int e = 0; e < 8; ++e)
                o[e] = T[(n8 + e) * 128 + ((g ^ rsw) * 8) + c7];
            *(u16x8*)&vT[vb0 + (size_t)hh * 131072 + (size_t)dd * 2048 + n8] = o;
        }
    }
}

// ---- Flash attention v6: v4 structure, kt-loop unrolled x2 (compile-time LDS buffers) ----
__global__ __launch_bounds__(256, 4) void flash_attn6(const __bf16* __restrict__ qkv,
                                                      const __bf16* __restrict__ vT,
                                                      __bf16* __restrict__ attnout) {
    __shared__ __bf16 Ks[2][4096];     // [64 kv-rows][64 d], granule ^= (row&7)
    __shared__ __bf16 Vs[2][4096];     // [64 d-rows][64 kv], granule ^= (row&7)

    const int tid = threadIdx.x, lane = tid & 63, wid = tid >> 6;
    const int i = lane & 15, qg = lane >> 4;

    // XCD-aware decode: XCD j gets whole heads
    const int n = blockIdx.x;                 // 0..1023
    const int j = n & 7, t = n >> 3;
    const int head = j * 8 + (t >> 4);        // 0..63
    const int b = head >> 4, h = head & 15;
    const int q0 = (t & 15) * 128;

    const size_t base  = (size_t)b * (2048 * 1024) + (size_t)h * 64;
    const size_t vbase = (size_t)head * (64 * 2048);

    // Q fragments: 2 groups of 16 q-rows, B-operand layout
    bf16x8 qf[2][2];
#pragma unroll
    for (int g = 0; g < 2; ++g) {
        int qrow = q0 + wid * 32 + g * 16 + i;
#pragma unroll
        for (int s = 0; s < 2; ++s)
            qf[g][s] = *(const bf16x8*)&qkv[base + (size_t)qrow * 1024 + s * 32 + qg * 8];
    }

    // staging source pointers (per-lane, pre-swizzled granule)
    const int r0s = tid >> 3, g0s = tid & 7;
    const __bf16* ksrc0 = &qkv[base + (size_t)r0s * 1024 + (size_t)((g0s ^ (r0s & 7)) * 8)];
    const __bf16* ksrc1 = ksrc0 + 32 * 1024;
    const __bf16* vsrc0 = &vT[vbase + (size_t)r0s * 2048 + (size_t)((g0s ^ (r0s & 7)) * 8)];
    const __bf16* vsrc1 = vsrc0 + 32 * 2048;

    auto STAGE = [&](int buf) {
        gload16(ksrc0, &Ks[buf][wid * 512]);
        gload16(ksrc1, &Ks[buf][2048 + wid * 512]);
        gload16(vsrc0, &Vs[buf][wid * 512]);
        gload16(vsrc1, &Vs[buf][2048 + wid * 512]);
        ksrc0 += 64 * 1024; ksrc1 += 64 * 1024;
        vsrc0 += 64;        vsrc1 += 64;
    };

    const float SL2E = 0.18033688f;           // 0.125 * log2(e)
    float m_run[2] = {-1e30f, -1e30f};
    float msc[2]   = {-1e30f, -1e30f};
    f32x4 po[2][4] = {};
    f32x4 po5[2]   = {};                      // row-sums l via ones-MFMA
    bf16x8 ones;
#pragma unroll
    for (int e = 0; e < 8; ++e) ones[e] = (__bf16)1.0f;

    auto BODY = [&](const __bf16* Kb, const __bf16* Vb) {
        __builtin_amdgcn_s_setprio(1);
        f32x4 st[2][4];
#pragma unroll
        for (int m = 0; m < 4; ++m) {
            bf16x8 kf0 = *(const bf16x8*)&Kb[(m * 16 + i) * 64 + ((qg) ^ (i & 7)) * 8];
            bf16x8 kf1 = *(const bf16x8*)&Kb[(m * 16 + i) * 64 + ((4 + qg) ^ (i & 7)) * 8];
            f32x4 z0 = {}, z1 = {};
            z0 = mfma16(kf0, qf[0][0], z0);
            st[0][m] = mfma16(kf1, qf[0][1], z0);
            z1 = mfma16(kf0, qf[1][0], z1);
            st[1][m] = mfma16(kf1, qf[1][1], z1);
        }
        __builtin_amdgcn_s_setprio(0);

        // softmax: shfl-free common path, trigger-only rescale; P stays in registers
        bf16x8 pa[2][2];
#pragma unroll
        for (int g = 0; g < 2; ++g) {
            f32x4 mv = __builtin_elementwise_max(st[g][0], st[g][1]);
            mv = __builtin_elementwise_max(mv, st[g][2]);
            mv = __builtin_elementwise_max(mv, st[g][3]);
            float rmv = fmaxf(fmaxf(mv[0], mv[1]), fmaxf(mv[2], mv[3]));

            if (__ballot(rmv > m_run[g] + 64.f)) {         // tile 0 only, in practice
                float rm = fmaxf(rmv, __shfl_xor(rmv, 16));
                rm = fmaxf(rm, __shfl_xor(rm, 32));
                float mnew  = fmaxf(m_run[g], rm);
                float alpha = fexp2(fmaf(m_run[g], SL2E, -mnew * SL2E));
                m_run[g] = mnew;
                msc[g]   = mnew * SL2E;
                float ar[4];
#pragma unroll
                for (int r = 0; r < 4; ++r) ar[r] = __shfl(alpha, qg * 4 + r);
#pragma unroll
                for (int nf = 0; nf < 4; ++nf) {
                    po[g][nf][0] *= ar[0]; po[g][nf][1] *= ar[1];
                    po[g][nf][2] *= ar[2]; po[g][nf][3] *= ar[3];
                }
                po5[g][0] *= ar[0]; po5[g][1] *= ar[1];
                po5[g][2] *= ar[2]; po5[g][3] *= ar[3];
            }

#pragma unroll
            for (int m = 0; m < 4; ++m)
#pragma unroll
                for (int r = 0; r < 4; ++r)
                    st[g][m][r] = fexp2(fmaf(st[g][m][r], SL2E, -msc[g]));

            // A-fragment in place: slot (s,e) <- st[2s + (e>>2)][e&3]
#pragma unroll
            for (int r = 0; r < 4; ++r) {
                pa[g][0][r]     = (__bf16)st[g][0][r];
                pa[g][0][4 + r] = (__bf16)st[g][1][r];
                pa[g][1][r]     = (__bf16)st[g][2][r];
                pa[g][1][4 + r] = (__bf16)st[g][3][r];
            }
        }

        // O += P V  (B reads LDS at the matching k-slot permutation)
        __builtin_amdgcn_s_setprio(1);
#pragma unroll
        for (int s = 0; s < 2; ++s) {
#pragma unroll
            for (int nf = 0; nf < 4; ++nf) {
                const int row = nf * 16 + i;
                bf16x8 vf;
                *(bf16x4*)&vf = *(const bf16x4*)
                    &Vb[row * 64 + (((s * 4 + (qg >> 1)) ^ (i & 7)) * 8 + (qg & 1) * 4)];
                *((bf16x4*)&vf + 1) = *(const bf16x4*)
                    &Vb[row * 64 + (((s * 4 + 2 + (qg >> 1)) ^ (i & 7)) * 8 + (qg & 1) * 4)];
                po[0][nf] = mfma16(pa[0][s], vf, po[0][nf]);
                po[1][nf] = mfma16(pa[1][s], vf, po[1][nf]);
            }
            po5[0] = mfma16(pa[0][s], ones, po5[0]);
            po5[1] = mfma16(pa[1][s], ones, po5[1]);
        }
        __builtin_amdgcn_s_setprio(0);
    };

    STAGE(0);
    __syncthreads();
    // unrolled x2: compile-time LDS buffer addresses in each body
    for (int kt2 = 0; kt2 < 16; ++kt2) {
        STAGE(1);                        // tile 2*kt2+1
        BODY(Ks[0], Vs[0]);              // tile 2*kt2
        __syncthreads();                 // buf1 staged; buf0 free
        if (kt2 < 15) STAGE(0);          // tile 2*kt2+2
        BODY(Ks[1], Vs[1]);              // tile 2*kt2+1
        __syncthreads();                 // buf0 staged; buf1 free
    }

    // epilogue: l is in po5 (all q-columns identical) — no shuffles
#pragma unroll
    for (int g = 0; g < 2; ++g) {
        float linv[4];
#pragma unroll
        for (int r = 0; r < 4; ++r) linv[r] = __builtin_amdgcn_rcpf(po5[g][r]);
#pragma unroll
        for (int nf = 0; nf < 4; ++nf)
#pragma unroll
            for (int r = 0; r < 4; ++r) {
                int row = q0 + wid * 32 + g * 16 + qg * 4 + r;
                attnout[base + (size_t)row * 1024 + nf * 16 + i] = (__bf16)(po[g][nf][r] * linv[r]);
            }
    }
}

extern "C" void kernel_launch(void* const* d_in, const int* in_sizes, int n_in,
                              void* d_out, int out_size, void* d_ws, size_t ws_size,
                              hipStream_t stream) {
    const float* x    = (const float*)d_in[0];
    const float* Wqkv = (const float*)d_in[1];
    const float* Wout = (const float*)d_in[2];
    const float* bout = (const float*)d_in[3];
    float* out = (float*)d_out;

    char* ws = (char*)d_ws;
    // [0,16M):  xb (x bf16; dead after gemm1) -> reused as aout (flash W, gemm2 R)
    // [16,32M): qkvb (gemm1 W, flash R)
    // [32,48M): vT  (gemm1 epilogue W, flash R)
    // [48,50M): wqt ; [50,52M): wot
    unsigned short* xb   = (unsigned short*)(ws);
    unsigned short* aout = (unsigned short*)(ws);
    unsigned short* qkvb = (unsigned short*)(ws + (16u << 20));
    __bf16*         vTp  = (__bf16*)(ws + (32u << 20));
    __bf16*         wqt  = (__bf16*)(ws + (48u << 20));
    __bf16*         wot  = (__bf16*)(ws + (50u << 20));

    cast_bf16<<<4096, 256, 0, stream>>>(x, xb);
    cast_transpose2<<<dim3(16, 16, 2), 256, 0, stream>>>(Wqkv, Wout, wqt, wot);

    // qkv = x @ W_qkv (bf16) + fused per-head V^T
    gemm_bt<true, true><<<dim3(8, 64), 256, 0, stream>>>(xb, (const unsigned short*)wqt,
                                                         qkvb, nullptr, vTp);

    flash_attn6<<<1024, 256, 0, stream>>>((const __bf16*)qkvb, vTp, (__bf16*)aout);

    // out = attn @ W_out + b (fp32)
    gemm_bt<false, false><<<dim3(8, 64), 256, 0, stream>>>(aout, (const unsigned short*)wot,
                                                           out, bout, nullptr);
}

// Round 8
// 141.911 us; speedup vs baseline: 3.7303x; 1.0762x over previous
//
#include <hip/hip_runtime.h>

typedef float  f32x4  __attribute__((ext_vector_type(4)));
typedef __bf16 bf16x8 __attribute__((ext_vector_type(8)));
typedef __bf16 bf16x4 __attribute__((ext_vector_type(4)));
typedef unsigned short u16x8 __attribute__((ext_vector_type(8)));

__device__ __forceinline__ unsigned short f2bf(float f) {
    unsigned u = __builtin_bit_cast(unsigned, f);
    unsigned r = u + 0x7FFFu + ((u >> 16) & 1u);   // round-to-nearest-even
    return (unsigned short)(r >> 16);
}

__device__ __forceinline__ f32x4 mfma16(bf16x8 a, bf16x8 b, f32x4 c) {
    return __builtin_amdgcn_mfma_f32_16x16x32_bf16(a, b, c, 0, 0, 0);
}
__device__ __forceinline__ f32x4 mfma16u(u16x8 a, u16x8 b, f32x4 c) {
    return __builtin_amdgcn_mfma_f32_16x16x32_bf16(
        __builtin_bit_cast(bf16x8, a), __builtin_bit_cast(bf16x8, b), c, 0, 0, 0);
}

__device__ __forceinline__ float fexp2(float x) {
    float r;
    asm("v_exp_f32 %0, %1" : "=v"(r) : "v"(x));
    return r;
}

// async global->LDS, 16B per lane, dest = wave-uniform base + lane*16
__device__ __forceinline__ void gload16(const void* g, void* l) {
    __builtin_amdgcn_global_load_lds((const __attribute__((address_space(1))) void*)g,
                                     (__attribute__((address_space(3))) void*)l,
                                     16, 0, 0);
}

// ---- cast + transpose both 1024x1024 weights: W[k][n] -> bf16 Wt[n][k] ----
__global__ __launch_bounds__(256) void cast_transpose2(const float* __restrict__ W0,
                                                       const float* __restrict__ W1,
                                                       __bf16* __restrict__ T0Q,
                                                       __bf16* __restrict__ T1Q) {
    const float* W = blockIdx.z ? W1 : W0;
    __bf16* Wt = blockIdx.z ? T1Q : T0Q;
    __shared__ __bf16 T[64][64];
    const int tid = threadIdx.x;
    const int k0 = blockIdx.y * 64, n0 = blockIdx.x * 64;
#pragma unroll
    for (int c = 0; c < 4; ++c) {
        int idx = c * 256 + tid;
        int kr = idx >> 4, nc = (idx & 15) * 4;
        f32x4 w = *(const f32x4*)&W[(size_t)(k0 + kr) * 1024 + n0 + nc];
        int g = ((nc >> 3) ^ (kr >> 3)) * 8 + (nc & 7);
        bf16x4 pk;
        pk[0] = (__bf16)w[0]; pk[1] = (__bf16)w[1];
        pk[2] = (__bf16)w[2]; pk[3] = (__bf16)w[3];
        *(bf16x4*)&T[kr][g] = pk;
    }
    __syncthreads();
#pragma unroll
    for (int c = 0; c < 2; ++c) {
        int idx = c * 256 + tid;
        int n = idx >> 3, k8 = (idx & 7) * 8;
        bf16x8 o;
#pragma unroll
        for (int e = 0; e < 8; ++e) {
            int k = k8 + e;
            o[e] = T[k][((n >> 3) ^ (k >> 3)) * 8 + (n & 7)];
        }
        *(bf16x8*)&Wt[(size_t)(n0 + n) * 1024 + k0 + k8] = o;
    }
}

// ---------------- GEMM + optional fused fp32->bf16 A-cast + fused V^T epilogue ----------------
// C[8192][1024] = A[8192][1024] * Bt[1024][1024]^T.
// CAST_A:   A is fp32; convert to bf16 in-register during LDS staging.
// WRITE_VT: additionally emit vT[(b*16+h)][d][n] via LDS transpose of the C tile.
template <bool OUT_BF16, bool WRITE_VT, bool CAST_A>
__global__ __launch_bounds__(256) void gemm_bt(const void* __restrict__ Av,
                                               const unsigned short* __restrict__ Bt,
                                               void* __restrict__ Cout,
                                               const float* __restrict__ bias,
                                               __bf16* __restrict__ vT) {
    constexpr int K = 1024, NN = 1024;
    __shared__ unsigned short SM[18432];            // As(128x72) | Bs(128x72); reused as T[128][128]
    typedef unsigned short u16_72[72];
    u16_72* As = (u16_72*)SM;
    u16_72* Bs = (u16_72*)(SM + 9216);
    const int tid  = threadIdx.x;
    const int lane = tid & 63, wid = tid >> 6;
    const int wm = wid >> 1, wn = wid & 1;
    const int i = lane & 15, q8 = (lane >> 4) * 8;
    // XCD-aware: 512 blocks, bijective swizzle; XCD j gets an 8x8 tile band
    const int bid = blockIdx.y * 8 + blockIdx.x;
    const int swz = (bid & 7) * 64 + (bid >> 3);
    const int tm = (swz >> 3) * 128, tn = (swz & 7) * 128;
    const int srow = tid >> 3, scol = (tid & 7) * 8;

    f32x4 acc[4][4] = {};

    for (int k0 = 0; k0 < K; k0 += 64) {
#pragma unroll
        for (int c = 0; c < 4; ++c) {
            int row = c * 32 + srow;
            u16x8 av;
            if constexpr (CAST_A) {
                const float* Af = (const float*)Av;
                const float* p = &Af[(size_t)(tm + row) * K + k0 + scol];
                f32x4 a0 = *(const f32x4*)p;
                f32x4 a1 = *(const f32x4*)(p + 4);
                av[0] = f2bf(a0[0]); av[1] = f2bf(a0[1]);
                av[2] = f2bf(a0[2]); av[3] = f2bf(a0[3]);
                av[4] = f2bf(a1[0]); av[5] = f2bf(a1[1]);
                av[6] = f2bf(a1[2]); av[7] = f2bf(a1[3]);
            } else {
                const unsigned short* Au = (const unsigned short*)Av;
                av = *(const u16x8*)&Au[(size_t)(tm + row) * K + k0 + scol];
            }
            u16x8 bv = *(const u16x8*)&Bt[(size_t)(tn + row) * K + k0 + scol];
            *(u16x8*)&As[row][scol] = av;
            *(u16x8*)&Bs[row][scol] = bv;
        }
        __syncthreads();
#pragma unroll
        for (int ks = 0; ks < 2; ++ks) {
            u16x8 af[4], bfr[4];
#pragma unroll
            for (int m = 0; m < 4; ++m) af[m]  = *(const u16x8*)&As[wm * 64 + m * 16 + i][ks * 32 + q8];
#pragma unroll
            for (int nn = 0; nn < 4; ++nn) bfr[nn] = *(const u16x8*)&Bs[wn * 64 + nn * 16 + i][ks * 32 + q8];
#pragma unroll
            for (int m = 0; m < 4; ++m)
#pragma unroll
                for (int nn = 0; nn < 4; ++nn)
                    acc[m][nn] = mfma16u(af[m], bfr[nn], acc[m][nn]);
        }
        __syncthreads();
    }

    const int r0 = (lane >> 4) * 4;
#pragma unroll
    for (int nn = 0; nn < 4; ++nn) {
        int col = tn + wn * 64 + nn * 16 + i;
        float bv = 0.f;
        if constexpr (!OUT_BF16) bv = bias[col];
#pragma unroll
        for (int m = 0; m < 4; ++m) {
            int rowb = tm + wm * 64 + m * 16 + r0;
#pragma unroll
            for (int r = 0; r < 4; ++r) {
                if constexpr (OUT_BF16)
                    ((unsigned short*)Cout)[(size_t)(rowb + r) * NN + col] = f2bf(acc[m][nn][r]);
                else
                    ((float*)Cout)[(size_t)(rowb + r) * NN + col] = acc[m][nn][r] + bv;
            }
        }
    }

    if constexpr (WRITE_VT) {
        // phase 1: acc -> granule-XOR-swizzled T[128][128] (overwrites As/Bs; all reads done)
        unsigned short* T = SM;
#pragma unroll
        for (int nn = 0; nn < 4; ++nn) {
            const int col = wn * 64 + nn * 16 + i;
            const int g = col >> 3, c7 = col & 7;
#pragma unroll
            for (int m = 0; m < 4; ++m) {
                const int rbase = wm * 64 + m * 16 + r0;        // r0..r0+3 share rbase>>3
                const int rsw = (rbase >> 3) & 15;
#pragma unroll
                for (int r = 0; r < 4; ++r)
                    T[(rbase + r) * 128 + ((g ^ rsw) * 8) + c7] = f2bf(acc[m][nn][r]);
            }
        }
        __syncthreads();
        // phase 2: coalesced 16B writes of vT[head][d][tm..tm+128)
        const size_t vb0 = ((size_t)(tm >> 11) * 16 + (tn >> 6)) * 131072 + (size_t)(tm & 2047);
#pragma unroll
        for (int c = 0; c < 8; ++c) {
            int idx = c * 256 + tid;                 // 0..2047
            int hh = idx >> 10, dd = (idx >> 4) & 63, n8 = (idx & 15) * 8;
            int g = (hh * 64 + dd) >> 3, c7 = dd & 7, rsw = idx & 15;
            u16x8 o;
#pragma unroll
            for (int e = 0; e < 8; ++e)
                o[e] = T[(n8 + e) * 128 + ((g ^ rsw) * 8) + c7];
            *(u16x8*)&vT[vb0 + (size_t)hh * 131072 + (size_t)dd * 2048 + n8] = o;
        }
    }
}

// ---- Flash attention v7: no-max softmax (scale cancels in O/l), in-register P ----
__global__ __launch_bounds__(256, 4) void flash_attn7(const __bf16* __restrict__ qkv,
                                                      const __bf16* __restrict__ vT,
                                                      __bf16* __restrict__ attnout) {
    __shared__ __bf16 Ks[2][4096];     // [64 kv-rows][64 d], granule ^= (row&7)
    __shared__ __bf16 Vs[2][4096];     // [64 d-rows][64 kv], granule ^= (row&7)

    const int tid = threadIdx.x, lane = tid & 63, wid = tid >> 6;
    const int i = lane & 15, qg = lane >> 4;

    // XCD-aware decode: XCD j gets whole heads
    const int n = blockIdx.x;                 // 0..1023
    const int j = n & 7, t = n >> 3;
    const int head = j * 8 + (t >> 4);        // 0..63
    const int b = head >> 4, h = head & 15;
    const int q0 = (t & 15) * 128;

    const size_t base  = (size_t)b * (2048 * 1024) + (size_t)h * 64;
    const size_t vbase = (size_t)head * (64 * 2048);

    // Q fragments: 2 groups of 16 q-rows, B-operand layout
    bf16x8 qf[2][2];
#pragma unroll
    for (int g = 0; g < 2; ++g) {
        int qrow = q0 + wid * 32 + g * 16 + i;
#pragma unroll
        for (int s = 0; s < 2; ++s)
            qf[g][s] = *(const bf16x8*)&qkv[base + (size_t)qrow * 1024 + s * 32 + qg * 8];
    }

    // staging source pointers (per-lane, pre-swizzled granule)
    const int r0s = tid >> 3, g0s = tid & 7;
    const __bf16* ksrc0 = &qkv[base + (size_t)r0s * 1024 + (size_t)((g0s ^ (r0s & 7)) * 8)];
    const __bf16* ksrc1 = ksrc0 + 32 * 1024;
    const __bf16* vsrc0 = &vT[vbase + (size_t)r0s * 2048 + (size_t)((g0s ^ (r0s & 7)) * 8)];
    const __bf16* vsrc1 = vsrc0 + 32 * 2048;

    auto STAGE = [&](int buf) {
        gload16(ksrc0, &Ks[buf][wid * 512]);
        gload16(ksrc1, &Ks[buf][2048 + wid * 512]);
        gload16(vsrc0, &Vs[buf][wid * 512]);
        gload16(vsrc1, &Vs[buf][2048 + wid * 512]);
        ksrc0 += 64 * 1024; ksrc1 += 64 * 1024;
        vsrc0 += 64;        vsrc1 += 64;
    };

    const float SL2E = 0.18033688f;           // 0.125 * log2(e)
    f32x4 po[2][4] = {};
    f32x4 po5[2]   = {};                      // row-sums l via ones-MFMA
    bf16x8 ones;
#pragma unroll
    for (int e = 0; e < 8; ++e) ones[e] = (__bf16)1.0f;

    // P' = 2^(S*SL2E) with NO max subtraction: the 2^m factor cancels in O/l.
    // Bound: |S| <= ||q||*||k|| ~ <=150 worst-case -> P' <= 2^27, l <= 2^38: f32-safe.
    auto BODY = [&](const __bf16* Kb, const __bf16* Vb) {
        __builtin_amdgcn_s_setprio(1);
        f32x4 st[2][4];
#pragma unroll
        for (int m = 0; m < 4; ++m) {
            bf16x8 kf0 = *(const bf16x8*)&Kb[(m * 16 + i) * 64 + ((qg) ^ (i & 7)) * 8];
            bf16x8 kf1 = *(const bf16x8*)&Kb[(m * 16 + i) * 64 + ((4 + qg) ^ (i & 7)) * 8];
            f32x4 z0 = {}, z1 = {};
            z0 = mfma16(kf0, qf[0][0], z0);
            st[0][m] = mfma16(kf1, qf[0][1], z0);
            z1 = mfma16(kf0, qf[1][0], z1);
            st[1][m] = mfma16(kf1, qf[1][1], z1);
        }
        __builtin_amdgcn_s_setprio(0);

        // softmax numerator: pure per-lane mul+exp+cvt, no reductions, no branches
        bf16x8 pa[2][2];
#pragma unroll
        for (int g = 0; g < 2; ++g) {
#pragma unroll
            for (int m = 0; m < 4; ++m)
#pragma unroll
                for (int r = 0; r < 4; ++r)
                    st[g][m][r] = fexp2(st[g][m][r] * SL2E);

            // A-fragment in place: slot (s,e) <- st[2s + (e>>2)][e&3]
#pragma unroll
            for (int r = 0; r < 4; ++r) {
                pa[g][0][r]     = (__bf16)st[g][0][r];
                pa[g][0][4 + r] = (__bf16)st[g][1][r];
                pa[g][1][r]     = (__bf16)st[g][2][r];
                pa[g][1][4 + r] = (__bf16)st[g][3][r];
            }
        }

        // O += P V  (B reads LDS at the matching k-slot permutation)
        __builtin_amdgcn_s_setprio(1);
#pragma unroll
        for (int s = 0; s < 2; ++s) {
#pragma unroll
            for (int nf = 0; nf < 4; ++nf) {
                const int row = nf * 16 + i;
                bf16x8 vf;
                *(bf16x4*)&vf = *(const bf16x4*)
                    &Vb[row * 64 + (((s * 4 + (qg >> 1)) ^ (i & 7)) * 8 + (qg & 1) * 4)];
                *((bf16x4*)&vf + 1) = *(const bf16x4*)
                    &Vb[row * 64 + (((s * 4 + 2 + (qg >> 1)) ^ (i & 7)) * 8 + (qg & 1) * 4)];
                po[0][nf] = mfma16(pa[0][s], vf, po[0][nf]);
                po[1][nf] = mfma16(pa[1][s], vf, po[1][nf]);
            }
            po5[0] = mfma16(pa[0][s], ones, po5[0]);
            po5[1] = mfma16(pa[1][s], ones, po5[1]);
        }
        __builtin_amdgcn_s_setprio(0);
    };

    STAGE(0);
    __syncthreads();
    // unrolled x2: compile-time LDS buffer addresses in each body
    for (int kt2 = 0; kt2 < 16; ++kt2) {
        STAGE(1);                        // tile 2*kt2+1
        BODY(Ks[0], Vs[0]);              // tile 2*kt2
        __syncthreads();                 // buf1 staged; buf0 free
        if (kt2 < 15) STAGE(0);          // tile 2*kt2+2
        BODY(Ks[1], Vs[1]);              // tile 2*kt2+1
        __syncthreads();                 // buf0 staged; buf1 free
    }

    // epilogue: l is in po5 (all q-columns identical) — no shuffles
#pragma unroll
    for (int g = 0; g < 2; ++g) {
        float linv[4];
#pragma unroll
        for (int r = 0; r < 4; ++r) linv[r] = __builtin_amdgcn_rcpf(po5[g][r]);
#pragma unroll
        for (int nf = 0; nf < 4; ++nf)
#pragma unroll
            for (int r = 0; r < 4; ++r) {
                int row = q0 + wid * 32 + g * 16 + qg * 4 + r;
                attnout[base + (size_t)row * 1024 + nf * 16 + i] = (__bf16)(po[g][nf][r] * linv[r]);
            }
    }
}

extern "C" void kernel_launch(void* const* d_in, const int* in_sizes, int n_in,
                              void* d_out, int out_size, void* d_ws, size_t ws_size,
                              hipStream_t stream) {
    const float* x    = (const float*)d_in[0];
    const float* Wqkv = (const float*)d_in[1];
    const float* Wout = (const float*)d_in[2];
    const float* bout = (const float*)d_in[3];
    float* out = (float*)d_out;

    char* ws = (char*)d_ws;
    // [0,16M):  aout (flash W, gemm2 R)
    // [16,32M): qkvb (gemm1 W, flash R)
    // [32,48M): vT  (gemm1 epilogue W, flash R)
    // [48,50M): wqt ; [50,52M): wot
    unsigned short* aout = (unsigned short*)(ws);
    unsigned short* qkvb = (unsigned short*)(ws + (16u << 20));
    __bf16*         vTp  = (__bf16*)(ws + (32u << 20));
    __bf16*         wqt  = (__bf16*)(ws + (48u << 20));
    __bf16*         wot  = (__bf16*)(ws + (50u << 20));

    cast_transpose2<<<dim3(16, 16, 2), 256, 0, stream>>>(Wqkv, Wout, wqt, wot);

    // qkv = bf16(x) @ W_qkv (bf16 out) + fused A-cast + fused per-head V^T
    gemm_bt<true, true, true><<<dim3(8, 64), 256, 0, stream>>>(x, (const unsigned short*)wqt,
                                                               qkvb, nullptr, vTp);

    flash_attn7<<<1024, 256, 0, stream>>>((const __bf16*)qkvb, vTp, (__bf16*)aout);

    // out = attn @ W_out + b (fp32)
    gemm_bt<false, false, false><<<dim3(8, 64), 256, 0, stream>>>(aout, (const unsigned short*)wot,
                                                                  out, bout, nullptr);
}